// Round 11
// baseline (321.322 us; speedup 1.0000x reference)
//
#include <hip/hip_runtime.h>
#include <stdint.h>

typedef float f32x4  __attribute__((ext_vector_type(4)));
typedef float f32x16 __attribute__((ext_vector_type(16)));
typedef short s16x8  __attribute__((ext_vector_type(8)));

// N=16, C=256, H=32, W=32, K=4096, M = N*H*W = 16384
// d_out layout (floats): quant[4194304] | code[16384] | logit[67108864] | v[1048576]
#define QUANT_OFF 0
#define CODE_OFF  4194304
#define LOGIT_OFF 4210688
#define V_OFF     71319552

// logit std ~= 0.0625 (codebook prescaled by 1/sqrt(C)); bf16-path absmax err 0.00195.
// Margin must exceed 2*err (0.0039); use 1/128 for 2x headroom.
#define ARGMAX_MARGIN 0.0078125f

__device__ __forceinline__ unsigned short f2bf(float f) {
  unsigned int u = __float_as_uint(f);
  u = u + 0x7fffu + ((u >> 16) & 1u);   // RNE
  return (unsigned short)(u >> 16);
}

__device__ __forceinline__ void load_lds16(const void* g, void* l) {
  __builtin_amdgcn_global_load_lds(
      (const __attribute__((address_space(1))) unsigned int*)g,
      (__attribute__((address_space(3))) unsigned int*)l, 16, 0, 0);
}

// ---------------- K1a: k = cb@wk^T, v = cb@wv^T (fp32 VALU GEMM) ----------------
__global__ __launch_bounds__(256) void kv_kernel(
    const float* __restrict__ cb, const float* __restrict__ wk, const float* __restrict__ wv,
    float* __restrict__ kf, unsigned short* __restrict__ kh, float* __restrict__ vout)
{
  __shared__ __align__(16) float Xs[64][260];
  const int t = threadIdx.x;
  const int rowBase = blockIdx.x * 64;
  const int colBase = blockIdx.y * 64;
  const f32x4* cb4 = (const f32x4*)cb;
  #pragma unroll
  for (int it = 0; it < 16; ++it) {
    int chunk = it * 256 + t;
    int row = chunk >> 6, kq = chunk & 63;
    f32x4 vv = cb4[(rowBase + row) * 64 + kq];
    *(f32x4*)&Xs[row][kq * 4] = vv;
  }
  __syncthreads();
  const int tx = t & 15, ty = t >> 4;
  const int c0 = colBase + tx * 4;
  float accK[4][4] = {{0.f}}, accV[4][4] = {{0.f}};
  const f32x4* wk4 = (const f32x4*)wk;
  const f32x4* wv4 = (const f32x4*)wv;
  #pragma unroll 2
  for (int kc = 0; kc < 64; ++kc) {
    f32x4 a[4];
    #pragma unroll
    for (int i = 0; i < 4; ++i) a[i] = *(const f32x4*)&Xs[ty * 4 + i][kc * 4];
    #pragma unroll
    for (int j = 0; j < 4; ++j) {
      f32x4 bk = wk4[(c0 + j) * 64 + kc];
      f32x4 bv = wv4[(c0 + j) * 64 + kc];
      #pragma unroll
      for (int i = 0; i < 4; ++i) {
        accK[i][j] = fmaf(a[i].x, bk.x, accK[i][j]);
        accK[i][j] = fmaf(a[i].y, bk.y, accK[i][j]);
        accK[i][j] = fmaf(a[i].z, bk.z, accK[i][j]);
        accK[i][j] = fmaf(a[i].w, bk.w, accK[i][j]);
        accV[i][j] = fmaf(a[i].x, bv.x, accV[i][j]);
        accV[i][j] = fmaf(a[i].y, bv.y, accV[i][j]);
        accV[i][j] = fmaf(a[i].z, bv.z, accV[i][j]);
        accV[i][j] = fmaf(a[i].w, bv.w, accV[i][j]);
      }
    }
  }
  #pragma unroll
  for (int i = 0; i < 4; ++i) {
    int r = rowBase + ty * 4 + i;
    f32x4 vk = {accK[i][0], accK[i][1], accK[i][2], accK[i][3]};
    f32x4 vv = {accV[i][0], accV[i][1], accV[i][2], accV[i][3]};
    *(f32x4*)&kf[r * 256 + c0] = vk;
    *(f32x4*)&vout[r * 256 + c0] = vv;
    ushort4 hk;
    hk.x = f2bf(accK[i][0]); hk.y = f2bf(accK[i][1]);
    hk.z = f2bf(accK[i][2]); hk.w = f2bf(accK[i][3]);
    *(ushort4*)&kh[r * 256 + c0] = hk;
  }
}

// ---------------- K1b: q = x@wq^T (fp32 VALU GEMM), qh = bf16(q/16) ----------------
__global__ __launch_bounds__(256) void q_kernel(
    const float* __restrict__ latent, const float* __restrict__ wq,
    float* __restrict__ qf, unsigned short* __restrict__ qh)
{
  __shared__ __align__(16) float Xs[64][260];
  const int t = threadIdx.x;
  const int rowBase = blockIdx.x * 64;
  const int n = rowBase >> 10;
  const int hw0 = rowBase & 1023;
  const int colBase = blockIdx.y * 64;
  const f32x4* lat4 = (const f32x4*)latent;
  #pragma unroll
  for (int it = 0; it < 16; ++it) {
    int chunk = it * 256 + t;
    int k = chunk >> 4, rq = chunk & 15;
    f32x4 vv = lat4[(n * 256 + k) * 256 + (hw0 >> 2) + rq];
    Xs[rq * 4 + 0][k] = vv.x;
    Xs[rq * 4 + 1][k] = vv.y;
    Xs[rq * 4 + 2][k] = vv.z;
    Xs[rq * 4 + 3][k] = vv.w;
  }
  __syncthreads();
  const int tx = t & 15, ty = t >> 4;
  const int c0 = colBase + tx * 4;
  float acc[4][4] = {{0.f}};
  const f32x4* wq4 = (const f32x4*)wq;
  #pragma unroll 2
  for (int kc = 0; kc < 64; ++kc) {
    f32x4 a[4];
    #pragma unroll
    for (int i = 0; i < 4; ++i) a[i] = *(const f32x4*)&Xs[ty * 4 + i][kc * 4];
    #pragma unroll
    for (int j = 0; j < 4; ++j) {
      f32x4 b = wq4[(c0 + j) * 64 + kc];
      #pragma unroll
      for (int i = 0; i < 4; ++i) {
        acc[i][j] = fmaf(a[i].x, b.x, acc[i][j]);
        acc[i][j] = fmaf(a[i].y, b.y, acc[i][j]);
        acc[i][j] = fmaf(a[i].z, b.z, acc[i][j]);
        acc[i][j] = fmaf(a[i].w, b.w, acc[i][j]);
      }
    }
  }
  #pragma unroll
  for (int i = 0; i < 4; ++i) {
    int r = rowBase + ty * 4 + i;
    f32x4 vq = {acc[i][0], acc[i][1], acc[i][2], acc[i][3]};
    *(f32x4*)&qf[r * 256 + c0] = vq;
    ushort4 hq;
    hq.x = f2bf(acc[i][0] * 0.0625f); hq.y = f2bf(acc[i][1] * 0.0625f);
    hq.z = f2bf(acc[i][2] * 0.0625f); hq.w = f2bf(acc[i][3] * 0.0625f);
    *(ushort4*)&qh[r * 256 + c0] = hq;
  }
}

// ---------------- K2: logit = qh @ kh^T (bf16 MFMA 32x32x16) + fused blockmax ----------------
// Same BK=32 double-buffered 1-sync-per-kt loop as the passing round-10 kernel.
// Changes: (a) 32x32x16 MFMA -> C rows map to col=lane&31 so every scalar store
// instruction writes 2x128B contiguous segments (vs 4x64B with 16x16);
// (b) swizzle gains a (row>>2)&3 XOR so 32-consecutive-row ds_read_b128 phases
// tile all 32 banks (16-lane phase spans {row*16+slot*4} cover 0..31 exactly 2x).
__global__ __launch_bounds__(256) void logit_gemm(
    const unsigned short* __restrict__ qh, const unsigned short* __restrict__ kh,
    float* __restrict__ out, float* __restrict__ pmax)
{
  __shared__ short AsBuf[2][128 * 32];
  __shared__ short BsBuf[2][128 * 32];
  __shared__ float Pm[128][2];
  const int t = threadIdx.x;
  const int bid = blockIdx.x;
  const int wg = (bid & 7) * 512 + (bid >> 3);  // XCD-chunked swizzle (4096 % 8 == 0)
  const int aRow0 = (wg >> 5) * 128;            // M block
  const int bRow0 = (wg & 31) * 128;            // N block
  const int lane = t & 63, wid = t >> 6;
  const int wr = wid >> 1, wc = wid & 1;
  f32x16 acc[2][2];
  #pragma unroll
  for (int m = 0; m < 2; ++m)
    #pragma unroll
    for (int n = 0; n < 2; ++n)
      #pragma unroll
      for (int j = 0; j < 16; ++j) acc[m][n][j] = 0.f;

  const short* qs = (const short*)qh;
  const short* ks = (const short*)kh;

  // 128x32 bf16 tile = 512 x 16B chunks per matrix; 2 chunks/thread each.
  // LDS linear dest (chunk c -> row=c>>2, lslot=c&3); source k-slot = lslot ^ swz(row).
  #define SWZ(row) (((row) & 3) ^ (((row) >> 2) & 3))
  #define STAGE32(AB, BB, KT) do {                                          \
    _Pragma("unroll")                                                       \
    for (int ci = 0; ci < 2; ++ci) {                                        \
      int c = ci * 256 + t;                                                 \
      int row = c >> 2;                                                     \
      int sk = (c & 3) ^ SWZ(row);                                          \
      int koff = (KT) * 32 + sk * 8;                                        \
      load_lds16(qs + (size_t)(aRow0 + row) * 256 + koff, (AB) + c * 8);    \
      load_lds16(ks + (size_t)(bRow0 + row) * 256 + koff, (BB) + c * 8);    \
    } } while (0)

  STAGE32(AsBuf[0], BsBuf[0], 0);
  #pragma unroll
  for (int kt = 0; kt < 8; ++kt) {
    const int buf = kt & 1;
    __syncthreads();                       // drains buf's loads; fences prev reads of buf^1
    if (kt < 7) STAGE32(AsBuf[buf ^ 1], BsBuf[buf ^ 1], kt + 1);
    const short* As = AsBuf[buf];
    const short* Bs = BsBuf[buf];
    #pragma unroll
    for (int kslice = 0; kslice < 2; ++kslice) {     // 16-k slices of the BK=32 tile
      const int sk = kslice * 2 + (lane >> 5);       // lane's k-slot within tile
      s16x8 af[2], bfr[2];
      #pragma unroll
      for (int m = 0; m < 2; ++m) {
        int row = wr * 64 + m * 32 + (lane & 31);
        af[m] = *(const s16x8*)(As + row * 32 + (sk ^ SWZ(row)) * 8);
      }
      #pragma unroll
      for (int n = 0; n < 2; ++n) {
        int row = wc * 64 + n * 32 + (lane & 31);
        bfr[n] = *(const s16x8*)(Bs + row * 32 + (sk ^ SWZ(row)) * 8);
      }
      #pragma unroll
      for (int m = 0; m < 2; ++m)
        #pragma unroll
        for (int n = 0; n < 2; ++n)
          acc[m][n] = __builtin_amdgcn_mfma_f32_32x32x16_bf16(af[m], bfr[n], acc[m][n], 0, 0, 0);
    }
  }
  #undef STAGE32
  #undef SWZ

  // fused blockmax: C row = (reg&3) + 8*(reg>>2) + 4*(lane>>5), col = lane&31 (m74/m101).
  // Per (m,reg): max over both n-frags, then 32-lane-group shfl reduce -> row max over 64 cols.
  #pragma unroll
  for (int m = 0; m < 2; ++m)
    #pragma unroll
    for (int reg = 0; reg < 16; ++reg) {
      float bm = fmaxf(acc[m][0][reg], acc[m][1][reg]);
      #pragma unroll
      for (int off = 1; off < 32; off <<= 1) bm = fmaxf(bm, __shfl_xor(bm, off));
      if ((lane & 31) == 0)
        Pm[wr * 64 + m * 32 + (reg & 3) + 8 * (reg >> 2) + 4 * (lane >> 5)][wc] = bm;
    }
  // logit store: per (m,n,reg) one instruction = 2 rows x 128B contiguous segments
  const int colL = lane & 31, rowOff = 4 * (lane >> 5);
  #pragma unroll
  for (int m = 0; m < 2; ++m)
    #pragma unroll
    for (int n = 0; n < 2; ++n) {
      const size_t rbase = (size_t)(aRow0 + wr * 64 + m * 32 + rowOff) * 4096
                         + bRow0 + wc * 64 + n * 32 + colL;
      #pragma unroll
      for (int reg = 0; reg < 16; ++reg)
        out[rbase + (size_t)((reg & 3) + 8 * (reg >> 2)) * 4096] = acc[m][n][reg];
    }
  __syncthreads();
  if (t < 128) pmax[(size_t)(aRow0 + t) * 32 + (bRow0 >> 7)] = fmaxf(Pm[t][0], Pm[t][1]);
}

// ---------------- K3: finalize — gmax from pmax, rescan candidate block(s), exact recheck, gather ----------------
// (verbatim from passing round 10)
__global__ __launch_bounds__(1024) void finalize_kernel(
    const float* __restrict__ logit, const float* __restrict__ pmax,
    const float* __restrict__ qf, const float* __restrict__ kf,
    const float* __restrict__ vout, float* __restrict__ quant, float* __restrict__ code)
{
  __shared__ __align__(16) float Vs[32][260];
  __shared__ int idxArr[32];
  const int t = threadIdx.x, wave = t >> 6, lane = t & 63;
  const int nh = blockIdx.x, n = nh >> 5, h = nh & 31;
  for (int ri = 0; ri < 2; ++ri) {
    const int w = wave * 2 + ri;
    const size_t r = (size_t)nh * 32 + w;
    float pv = -3e38f;
    if (lane < 32) pv = pmax[r * 32 + lane];
    float gmax = pv;
    #pragma unroll
    for (int off = 32; off; off >>= 1) gmax = fmaxf(gmax, __shfl_xor(gmax, off));
    const float thr = gmax - ARGMAX_MARGIN;
    unsigned long long bm = __ballot(pv >= thr); // candidate 128-col blocks (usually 1)
    const f32x4 qv = ((const f32x4*)(qf + r * 256))[lane];
    float bestV = -3e38f; int bestJ = 0x7fffffff;
    #pragma unroll 1
    while (bm) {
      const int nb = __ffsll(bm) - 1; bm &= bm - 1;
      const float2 lv = *(const float2*)&logit[r * 4096 + nb * 128 + lane * 2];
      unsigned long long c0 = __ballot(lv.x >= thr);
      unsigned long long c1 = __ballot(lv.y >= thr);
      #pragma unroll 1
      for (int half = 0; half < 2; ++half) {
        unsigned long long mm = half ? c1 : c0;
        #pragma unroll 1
        while (mm) {
          const int L = __ffsll(mm) - 1; mm &= mm - 1;
          const int j = nb * 128 + L * 2 + half;
          const f32x4 kv = ((const f32x4*)(kf + (size_t)j * 256))[lane];
          double s = (double)qv.x * kv.x + (double)qv.y * kv.y
                   + (double)qv.z * kv.z + (double)qv.w * kv.w;
          #pragma unroll
          for (int off = 32; off; off >>= 1) s += __shfl_xor(s, off);
          const float val = (float)(s * 0.0625);
          if (val > bestV || (val == bestV && j < bestJ)) { bestV = val; bestJ = j; }
        }
      }
    }
    if (lane == 0) idxArr[w] = bestJ;
  }
  __syncthreads();
  // stage the 32 selected v-rows in LDS (coalesced reads)
  for (int ri = 0; ri < 2; ++ri) {
    const int w2 = wave * 2 + ri;
    const int idx = idxArr[w2];
    const f32x4 vv = ((const f32x4*)(vout + (size_t)idx * 256))[lane];
    *(f32x4*)&Vs[w2][lane * 4] = vv;
  }
  __syncthreads();
  // transposed write: quant[n][c][h][w], w contiguous
  const int wcol = t & 31, cg = t >> 5;
  #pragma unroll
  for (int cc = 0; cc < 8; ++cc) {
    const int c = cg * 8 + cc;
    quant[(((size_t)n * 256 + c) * 32 + h) * 32 + wcol] = Vs[wcol][c];
  }
  if (t < 32) code[nh * 32 + t] = (float)(idxArr[t] & 255);
}

extern "C" void kernel_launch(void* const* d_in, const int* in_sizes, int n_in,
                              void* d_out, int out_size, void* d_ws, size_t ws_size,
                              hipStream_t stream) {
  (void)in_sizes; (void)n_in; (void)out_size; (void)ws_size;
  const float* latent = (const float*)d_in[0];
  const float* cb     = (const float*)d_in[1];
  const float* wq     = (const float*)d_in[2];
  const float* wk     = (const float*)d_in[3];
  const float* wv     = (const float*)d_in[4];

  float* out   = (float*)d_out;
  float* quant = out + QUANT_OFF;
  float* code  = out + CODE_OFF;
  float* logit = out + LOGIT_OFF;
  float* vout  = out + V_OFF;

  char* ws = (char*)d_ws;
  float*          qf   = (float*)(ws + 0);                 // 16 MB
  float*          kf   = (float*)(ws + 16777216);          // 4 MB
  unsigned short* qh   = (unsigned short*)(ws + 20971520); // 8 MB
  unsigned short* kh   = (unsigned short*)(ws + 29360128); // 2 MB
  float*          pmax = (float*)(ws + 31457280);          // 2 MB (16384 x 32)

  kv_kernel<<<dim3(64, 4), 256, 0, stream>>>(cb, wk, wv, kf, kh, vout);
  q_kernel<<<dim3(256, 4), 256, 0, stream>>>(latent, wq, qf, qh);
  logit_gemm<<<4096, 256, 0, stream>>>(qh, kh, logit, pmax);
  finalize_kernel<<<512, 1024, 0, stream>>>(logit, pmax, qf, kf, vout, quant, code);
}

// Round 12
// 310.034 us; speedup vs baseline: 1.0364x; 1.0364x over previous
//
#include <hip/hip_runtime.h>
#include <stdint.h>

typedef float f32x4 __attribute__((ext_vector_type(4)));
typedef short s16x8 __attribute__((ext_vector_type(8)));

// N=16, C=256, H=32, W=32, K=4096, M = N*H*W = 16384
// d_out layout (floats): quant[4194304] | code[16384] | logit[67108864] | v[1048576]
#define QUANT_OFF 0
#define CODE_OFF  4194304
#define LOGIT_OFF 4210688
#define V_OFF     71319552

// logit std ~= 0.0625 (codebook prescaled by 1/sqrt(C)); bf16-path absmax err 0.00195.
// Margin must exceed 2*err (0.0039); use 1/128 for 2x headroom.
#define ARGMAX_MARGIN 0.0078125f

__device__ __forceinline__ unsigned short f2bf(float f) {
  unsigned int u = __float_as_uint(f);
  u = u + 0x7fffu + ((u >> 16) & 1u);   // RNE
  return (unsigned short)(u >> 16);
}

__device__ __forceinline__ void load_lds16(const void* g, void* l) {
  __builtin_amdgcn_global_load_lds(
      (const __attribute__((address_space(1))) unsigned int*)g,
      (__attribute__((address_space(3))) unsigned int*)l, 16, 0, 0);
}

// ---------------- K1a: k = cb@wk^T, v = cb@wv^T (fp32 VALU GEMM) ----------------
__global__ __launch_bounds__(256) void kv_kernel(
    const float* __restrict__ cb, const float* __restrict__ wk, const float* __restrict__ wv,
    float* __restrict__ kf, unsigned short* __restrict__ kh, float* __restrict__ vout)
{
  __shared__ __align__(16) float Xs[64][260];
  const int t = threadIdx.x;
  const int rowBase = blockIdx.x * 64;
  const int colBase = blockIdx.y * 64;
  const f32x4* cb4 = (const f32x4*)cb;
  #pragma unroll
  for (int it = 0; it < 16; ++it) {
    int chunk = it * 256 + t;
    int row = chunk >> 6, kq = chunk & 63;
    f32x4 vv = cb4[(rowBase + row) * 64 + kq];
    *(f32x4*)&Xs[row][kq * 4] = vv;
  }
  __syncthreads();
  const int tx = t & 15, ty = t >> 4;
  const int c0 = colBase + tx * 4;
  float accK[4][4] = {{0.f}}, accV[4][4] = {{0.f}};
  const f32x4* wk4 = (const f32x4*)wk;
  const f32x4* wv4 = (const f32x4*)wv;
  #pragma unroll 2
  for (int kc = 0; kc < 64; ++kc) {
    f32x4 a[4];
    #pragma unroll
    for (int i = 0; i < 4; ++i) a[i] = *(const f32x4*)&Xs[ty * 4 + i][kc * 4];
    #pragma unroll
    for (int j = 0; j < 4; ++j) {
      f32x4 bk = wk4[(c0 + j) * 64 + kc];
      f32x4 bv = wv4[(c0 + j) * 64 + kc];
      #pragma unroll
      for (int i = 0; i < 4; ++i) {
        accK[i][j] = fmaf(a[i].x, bk.x, accK[i][j]);
        accK[i][j] = fmaf(a[i].y, bk.y, accK[i][j]);
        accK[i][j] = fmaf(a[i].z, bk.z, accK[i][j]);
        accK[i][j] = fmaf(a[i].w, bk.w, accK[i][j]);
        accV[i][j] = fmaf(a[i].x, bv.x, accV[i][j]);
        accV[i][j] = fmaf(a[i].y, bv.y, accV[i][j]);
        accV[i][j] = fmaf(a[i].z, bv.z, accV[i][j]);
        accV[i][j] = fmaf(a[i].w, bv.w, accV[i][j]);
      }
    }
  }
  #pragma unroll
  for (int i = 0; i < 4; ++i) {
    int r = rowBase + ty * 4 + i;
    f32x4 vk = {accK[i][0], accK[i][1], accK[i][2], accK[i][3]};
    f32x4 vv = {accV[i][0], accV[i][1], accV[i][2], accV[i][3]};
    __builtin_nontemporal_store(vk, (f32x4*)&kf[r * 256 + c0]);   // kf: sparse re-read
    *(f32x4*)&vout[r * 256 + c0] = vv;                            // vout: fully re-read (keep cached)
    ushort4 hk;
    hk.x = f2bf(accK[i][0]); hk.y = f2bf(accK[i][1]);
    hk.z = f2bf(accK[i][2]); hk.w = f2bf(accK[i][3]);
    *(ushort4*)&kh[r * 256 + c0] = hk;                            // kh: heavily re-read by K2
  }
}

// ---------------- K1b: q = x@wq^T (fp32 VALU GEMM), qh = bf16(q/16) ----------------
__global__ __launch_bounds__(256) void q_kernel(
    const float* __restrict__ latent, const float* __restrict__ wq,
    float* __restrict__ qf, unsigned short* __restrict__ qh)
{
  __shared__ __align__(16) float Xs[64][260];
  const int t = threadIdx.x;
  const int rowBase = blockIdx.x * 64;
  const int n = rowBase >> 10;
  const int hw0 = rowBase & 1023;
  const int colBase = blockIdx.y * 64;
  const f32x4* lat4 = (const f32x4*)latent;
  #pragma unroll
  for (int it = 0; it < 16; ++it) {
    int chunk = it * 256 + t;
    int k = chunk >> 4, rq = chunk & 15;
    f32x4 vv = lat4[(n * 256 + k) * 256 + (hw0 >> 2) + rq];
    Xs[rq * 4 + 0][k] = vv.x;
    Xs[rq * 4 + 1][k] = vv.y;
    Xs[rq * 4 + 2][k] = vv.z;
    Xs[rq * 4 + 3][k] = vv.w;
  }
  __syncthreads();
  const int tx = t & 15, ty = t >> 4;
  const int c0 = colBase + tx * 4;
  float acc[4][4] = {{0.f}};
  const f32x4* wq4 = (const f32x4*)wq;
  #pragma unroll 2
  for (int kc = 0; kc < 64; ++kc) {
    f32x4 a[4];
    #pragma unroll
    for (int i = 0; i < 4; ++i) a[i] = *(const f32x4*)&Xs[ty * 4 + i][kc * 4];
    #pragma unroll
    for (int j = 0; j < 4; ++j) {
      f32x4 b = wq4[(c0 + j) * 64 + kc];
      #pragma unroll
      for (int i = 0; i < 4; ++i) {
        acc[i][j] = fmaf(a[i].x, b.x, acc[i][j]);
        acc[i][j] = fmaf(a[i].y, b.y, acc[i][j]);
        acc[i][j] = fmaf(a[i].z, b.z, acc[i][j]);
        acc[i][j] = fmaf(a[i].w, b.w, acc[i][j]);
      }
    }
  }
  #pragma unroll
  for (int i = 0; i < 4; ++i) {
    int r = rowBase + ty * 4 + i;
    f32x4 vq = {acc[i][0], acc[i][1], acc[i][2], acc[i][3]};
    __builtin_nontemporal_store(vq, (f32x4*)&qf[r * 256 + c0]);   // qf: sparse re-read
    ushort4 hq;
    hq.x = f2bf(acc[i][0] * 0.0625f); hq.y = f2bf(acc[i][1] * 0.0625f);
    hq.z = f2bf(acc[i][2] * 0.0625f); hq.w = f2bf(acc[i][3] * 0.0625f);
    *(ushort4*)&qh[r * 256 + c0] = hq;                            // qh: heavily re-read by K2
  }
}

// ---------------- K2: logit = qh @ kh^T (bf16 MFMA) + fused blockmax ----------------
// Round-10 proven structure verbatim; ONLY change: logit stores are non-temporal
// (268 MB streamed once, ~3% re-read -> skip L2 write-allocate).
__global__ __launch_bounds__(256) void logit_gemm(
    const unsigned short* __restrict__ qh, const unsigned short* __restrict__ kh,
    float* __restrict__ out, float* __restrict__ pmax)
{
  __shared__ short AsBuf[2][128 * 32];
  __shared__ short BsBuf[2][128 * 32];
  __shared__ float Pm[128][2];
  const int t = threadIdx.x;
  const int bid = blockIdx.x;
  const int wg = (bid & 7) * 512 + (bid >> 3);  // XCD-chunked swizzle (4096 % 8 == 0)
  const int aRow0 = (wg >> 5) * 128;            // M block
  const int bRow0 = (wg & 31) * 128;            // N block
  const int lane = t & 63, wid = t >> 6;
  const int wr = wid >> 1, wc = wid & 1;
  f32x4 acc[4][4];
  #pragma unroll
  for (int m = 0; m < 4; ++m)
    #pragma unroll
    for (int n = 0; n < 4; ++n) { acc[m][n].x = 0.f; acc[m][n].y = 0.f; acc[m][n].z = 0.f; acc[m][n].w = 0.f; }

  const short* qs = (const short*)qh;
  const short* ks = (const short*)kh;

  #define STAGE32(AB, BB, KT) do {                                          \
    _Pragma("unroll")                                                       \
    for (int ci = 0; ci < 2; ++ci) {                                        \
      int c = ci * 256 + t;                                                 \
      int row = c >> 2;                                                     \
      int slot = (c & 3) ^ (row & 3);                                       \
      int koff = (KT) * 32 + slot * 8;                                      \
      load_lds16(qs + (size_t)(aRow0 + row) * 256 + koff, (AB) + c * 8);    \
      load_lds16(ks + (size_t)(bRow0 + row) * 256 + koff, (BB) + c * 8);    \
    } } while (0)

  STAGE32(AsBuf[0], BsBuf[0], 0);
  #pragma unroll
  for (int kt = 0; kt < 8; ++kt) {
    const int buf = kt & 1;
    __syncthreads();                       // drains buf's loads; fences prev reads of buf^1
    if (kt < 7) STAGE32(AsBuf[buf ^ 1], BsBuf[buf ^ 1], kt + 1);
    const short* As = AsBuf[buf];
    const short* Bs = BsBuf[buf];
    s16x8 af[4], bfr[4];
    #pragma unroll
    for (int m = 0; m < 4; ++m) {
      int row = wr * 64 + m * 16 + (lane & 15);
      int slot = (lane >> 4) ^ (row & 3);
      af[m] = *(const s16x8*)(As + row * 32 + slot * 8);
    }
    #pragma unroll
    for (int n = 0; n < 4; ++n) {
      int row = wc * 64 + n * 16 + (lane & 15);
      int slot = (lane >> 4) ^ (row & 3);
      bfr[n] = *(const s16x8*)(Bs + row * 32 + slot * 8);
    }
    #pragma unroll
    for (int m = 0; m < 4; ++m)
      #pragma unroll
      for (int n = 0; n < 4; ++n)
        acc[m][n] = __builtin_amdgcn_mfma_f32_16x16x32_bf16(af[m], bfr[n], acc[m][n], 0, 0, 0);
  }
  #undef STAGE32

  // fused blockmax: per (row, this 128-col block) max, into Pm then pmax
  #pragma unroll
  for (int m = 0; m < 4; ++m)
    #pragma unroll
    for (int j = 0; j < 4; ++j) {
      float bm = fmaxf(fmaxf(acc[m][0][j], acc[m][1][j]),
                       fmaxf(acc[m][2][j], acc[m][3][j]));
      #pragma unroll
      for (int off = 1; off < 16; off <<= 1) bm = fmaxf(bm, __shfl_xor(bm, off));
      if ((lane & 15) == 0) Pm[wr * 64 + m * 16 + (lane >> 4) * 4 + j][wc] = bm;
    }
  // logit store: proven scalar pattern, now non-temporal (no L2 write-allocate)
  const int colLane = lane & 15, rowQuad = (lane >> 4) * 4;
  #pragma unroll
  for (int m = 0; m < 4; ++m)
    #pragma unroll
    for (int n = 0; n < 4; ++n) {
      int row = aRow0 + wr * 64 + m * 16 + rowQuad;
      int col = bRow0 + wc * 64 + n * 16 + colLane;
      #pragma unroll
      for (int j = 0; j < 4; ++j)
        __builtin_nontemporal_store(acc[m][n][j], &out[(size_t)(row + j) * 4096 + col]);
    }
  __syncthreads();
  if (t < 128) pmax[(size_t)(aRow0 + t) * 32 + (bRow0 >> 7)] = fmaxf(Pm[t][0], Pm[t][1]);
}

// ---------------- K3: finalize — single-candidate fast path + exact recheck fallback ----------------
// If exactly ONE column is within margin of gmax, it is provably the argmax (margin
// covers 2x the bf16 logit error) -> skip qf/kf loads and the serial f64 chain.
__global__ __launch_bounds__(1024) void finalize_kernel(
    const float* __restrict__ logit, const float* __restrict__ pmax,
    const float* __restrict__ qf, const float* __restrict__ kf,
    const float* __restrict__ vout, float* __restrict__ quant, float* __restrict__ code)
{
  __shared__ __align__(16) float Vs[32][260];
  __shared__ int idxArr[32];
  const int t = threadIdx.x, wave = t >> 6, lane = t & 63;
  const int nh = blockIdx.x, n = nh >> 5, h = nh & 31;
  for (int ri = 0; ri < 2; ++ri) {
    const int w = wave * 2 + ri;
    const size_t r = (size_t)nh * 32 + w;
    float pv = -3e38f;
    if (lane < 32) pv = pmax[r * 32 + lane];
    float gmax = pv;
    #pragma unroll
    for (int off = 32; off; off >>= 1) gmax = fmaxf(gmax, __shfl_xor(gmax, off));
    const float thr = gmax - ARGMAX_MARGIN;
    const unsigned long long bmAll = __ballot(pv >= thr);  // candidate 128-col blocks
    // pass 1: count candidate columns, record the first one
    int tot = 0, firstJ = 0x7fffffff;
    {
      unsigned long long bm = bmAll;
      #pragma unroll 1
      while (bm) {
        const int nb = __ffsll(bm) - 1; bm &= bm - 1;
        const float2 lv = *(const float2*)&logit[r * 4096 + nb * 128 + lane * 2];
        unsigned long long c0 = __ballot(lv.x >= thr);
        unsigned long long c1 = __ballot(lv.y >= thr);
        tot += __popcll(c0) + __popcll(c1);
        if (firstJ == 0x7fffffff && (c0 | c1)) {
          int j0 = c0 ? nb * 128 + 2 * (__ffsll(c0) - 1)     : 0x7fffffff;
          int j1 = c1 ? nb * 128 + 2 * (__ffsll(c1) - 1) + 1 : 0x7fffffff;
          firstJ = j0 < j1 ? j0 : j1;
        }
      }
    }
    int bestJ = firstJ;
    if (tot > 1) {     // slow path: exact f64 recheck of every candidate
      const f32x4 qv = ((const f32x4*)(qf + r * 256))[lane];
      float bestV = -3e38f; bestJ = 0x7fffffff;
      unsigned long long bm = bmAll;
      #pragma unroll 1
      while (bm) {
        const int nb = __ffsll(bm) - 1; bm &= bm - 1;
        const float2 lv = *(const float2*)&logit[r * 4096 + nb * 128 + lane * 2];
        unsigned long long c0 = __ballot(lv.x >= thr);
        unsigned long long c1 = __ballot(lv.y >= thr);
        #pragma unroll 1
        for (int half = 0; half < 2; ++half) {
          unsigned long long mm = half ? c1 : c0;
          #pragma unroll 1
          while (mm) {
            const int L = __ffsll(mm) - 1; mm &= mm - 1;
            const int j = nb * 128 + L * 2 + half;
            const f32x4 kv = ((const f32x4*)(kf + (size_t)j * 256))[lane];
            double s = (double)qv.x * kv.x + (double)qv.y * kv.y
                     + (double)qv.z * kv.z + (double)qv.w * kv.w;
            #pragma unroll
            for (int off = 32; off; off >>= 1) s += __shfl_xor(s, off);
            const float val = (float)(s * 0.0625);
            if (val > bestV || (val == bestV && j < bestJ)) { bestV = val; bestJ = j; }
          }
        }
      }
    }
    if (lane == 0) idxArr[w] = bestJ;
  }
  __syncthreads();
  // stage the 32 selected v-rows in LDS (coalesced reads)
  for (int ri = 0; ri < 2; ++ri) {
    const int w2 = wave * 2 + ri;
    const int idx = idxArr[w2];
    const f32x4 vv = ((const f32x4*)(vout + (size_t)idx * 256))[lane];
    *(f32x4*)&Vs[w2][lane * 4] = vv;
  }
  __syncthreads();
  // transposed write: quant[n][c][h][w], w contiguous
  const int wcol = t & 31, cg = t >> 5;
  #pragma unroll
  for (int cc = 0; cc < 8; ++cc) {
    const int c = cg * 8 + cc;
    quant[(((size_t)n * 256 + c) * 32 + h) * 32 + wcol] = Vs[wcol][c];
  }
  if (t < 32) code[nh * 32 + t] = (float)(idxArr[t] & 255);
}

extern "C" void kernel_launch(void* const* d_in, const int* in_sizes, int n_in,
                              void* d_out, int out_size, void* d_ws, size_t ws_size,
                              hipStream_t stream) {
  (void)in_sizes; (void)n_in; (void)out_size; (void)ws_size;
  const float* latent = (const float*)d_in[0];
  const float* cb     = (const float*)d_in[1];
  const float* wq     = (const float*)d_in[2];
  const float* wk     = (const float*)d_in[3];
  const float* wv     = (const float*)d_in[4];

  float* out   = (float*)d_out;
  float* quant = out + QUANT_OFF;
  float* code  = out + CODE_OFF;
  float* logit = out + LOGIT_OFF;
  float* vout  = out + V_OFF;

  char* ws = (char*)d_ws;
  float*          qf   = (float*)(ws + 0);                 // 16 MB
  float*          kf   = (float*)(ws + 16777216);          // 4 MB
  unsigned short* qh   = (unsigned short*)(ws + 20971520); // 8 MB
  unsigned short* kh   = (unsigned short*)(ws + 29360128); // 2 MB
  float*          pmax = (float*)(ws + 31457280);          // 2 MB (16384 x 32)

  kv_kernel<<<dim3(64, 4), 256, 0, stream>>>(cb, wk, wv, kf, kh, vout);
  q_kernel<<<dim3(256, 4), 256, 0, stream>>>(latent, wq, qf, qh);
  logit_gemm<<<4096, 256, 0, stream>>>(qh, kh, logit, pmax);
  finalize_kernel<<<512, 1024, 0, stream>>>(logit, pmax, qf, kf, vout, quant, code);
}

// Round 13
// 295.360 us; speedup vs baseline: 1.0879x; 1.0497x over previous
//
#include <hip/hip_runtime.h>
#include <stdint.h>

typedef float f32x4 __attribute__((ext_vector_type(4)));
typedef short s16x8 __attribute__((ext_vector_type(8)));

// N=16, C=256, H=32, W=32, K=4096, M = N*H*W = 16384
// d_out layout (floats): quant[4194304] | code[16384] | logit[67108864] | v[1048576]
#define QUANT_OFF 0
#define CODE_OFF  4194304
#define LOGIT_OFF 4210688
#define V_OFF     71319552

// logit std ~= 0.0625 (codebook prescaled by 1/sqrt(C)); bf16-path absmax err 0.00195.
// Margin must exceed 2*err (0.0039); use 1/128 for 2x headroom.
#define ARGMAX_MARGIN 0.0078125f

__device__ __forceinline__ unsigned short f2bf(float f) {
  unsigned int u = __float_as_uint(f);
  u = u + 0x7fffu + ((u >> 16) & 1u);   // RNE
  return (unsigned short)(u >> 16);
}

__device__ __forceinline__ void load_lds16(const void* g, void* l) {
  __builtin_amdgcn_global_load_lds(
      (const __attribute__((address_space(1))) unsigned int*)g,
      (__attribute__((address_space(3))) unsigned int*)l, 16, 0, 0);
}

// ---------------- K1: merged q = x@wq^T (blocks 0..1023) and k/v = cb@w^T (blocks 1024..1279) ----------------
__global__ __launch_bounds__(256) void kvq_kernel(
    const float* __restrict__ latent, const float* __restrict__ wq,
    const float* __restrict__ cb, const float* __restrict__ wk, const float* __restrict__ wv,
    float* __restrict__ qf, unsigned short* __restrict__ qh,
    float* __restrict__ kf, unsigned short* __restrict__ kh, float* __restrict__ vout)
{
  __shared__ __align__(16) float Xs[64][260];
  const int t = threadIdx.x;
  const int bid = blockIdx.x;
  if (bid < 1024) {
    // ---- q path (was q_kernel, grid (256,4)) ----
    const int rowBase = (bid & 255) * 64;
    const int colBase = (bid >> 8) * 64;
    const int n = rowBase >> 10;
    const int hw0 = rowBase & 1023;
    const f32x4* lat4 = (const f32x4*)latent;
    #pragma unroll
    for (int it = 0; it < 16; ++it) {
      int chunk = it * 256 + t;
      int k = chunk >> 4, rq = chunk & 15;
      f32x4 vv = lat4[(n * 256 + k) * 256 + (hw0 >> 2) + rq];
      Xs[rq * 4 + 0][k] = vv.x;
      Xs[rq * 4 + 1][k] = vv.y;
      Xs[rq * 4 + 2][k] = vv.z;
      Xs[rq * 4 + 3][k] = vv.w;
    }
    __syncthreads();
    const int tx = t & 15, ty = t >> 4;
    const int c0 = colBase + tx * 4;
    float acc[4][4] = {{0.f}};
    const f32x4* wq4 = (const f32x4*)wq;
    #pragma unroll 2
    for (int kc = 0; kc < 64; ++kc) {
      f32x4 a[4];
      #pragma unroll
      for (int i = 0; i < 4; ++i) a[i] = *(const f32x4*)&Xs[ty * 4 + i][kc * 4];
      #pragma unroll
      for (int j = 0; j < 4; ++j) {
        f32x4 b = wq4[(c0 + j) * 64 + kc];
        #pragma unroll
        for (int i = 0; i < 4; ++i) {
          acc[i][j] = fmaf(a[i].x, b.x, acc[i][j]);
          acc[i][j] = fmaf(a[i].y, b.y, acc[i][j]);
          acc[i][j] = fmaf(a[i].z, b.z, acc[i][j]);
          acc[i][j] = fmaf(a[i].w, b.w, acc[i][j]);
        }
      }
    }
    #pragma unroll
    for (int i = 0; i < 4; ++i) {
      int r = rowBase + ty * 4 + i;
      f32x4 vq = {acc[i][0], acc[i][1], acc[i][2], acc[i][3]};
      *(f32x4*)&qf[r * 256 + c0] = vq;
      ushort4 hq;
      hq.x = f2bf(acc[i][0] * 0.0625f); hq.y = f2bf(acc[i][1] * 0.0625f);
      hq.z = f2bf(acc[i][2] * 0.0625f); hq.w = f2bf(acc[i][3] * 0.0625f);
      *(ushort4*)&qh[r * 256 + c0] = hq;
    }
  } else {
    // ---- k/v path (was kv_kernel, grid (64,4)) ----
    const int kb = bid - 1024;
    const int rowBase = (kb & 63) * 64;
    const int colBase = (kb >> 6) * 64;
    const f32x4* cb4 = (const f32x4*)cb;
    #pragma unroll
    for (int it = 0; it < 16; ++it) {
      int chunk = it * 256 + t;
      int row = chunk >> 6, kq = chunk & 63;
      f32x4 vv = cb4[(rowBase + row) * 64 + kq];
      *(f32x4*)&Xs[row][kq * 4] = vv;
    }
    __syncthreads();
    const int tx = t & 15, ty = t >> 4;
    const int c0 = colBase + tx * 4;
    float accK[4][4] = {{0.f}}, accV[4][4] = {{0.f}};
    const f32x4* wk4 = (const f32x4*)wk;
    const f32x4* wv4 = (const f32x4*)wv;
    #pragma unroll 2
    for (int kc = 0; kc < 64; ++kc) {
      f32x4 a[4];
      #pragma unroll
      for (int i = 0; i < 4; ++i) a[i] = *(const f32x4*)&Xs[ty * 4 + i][kc * 4];
      #pragma unroll
      for (int j = 0; j < 4; ++j) {
        f32x4 bk = wk4[(c0 + j) * 64 + kc];
        f32x4 bv = wv4[(c0 + j) * 64 + kc];
        #pragma unroll
        for (int i = 0; i < 4; ++i) {
          accK[i][j] = fmaf(a[i].x, bk.x, accK[i][j]);
          accK[i][j] = fmaf(a[i].y, bk.y, accK[i][j]);
          accK[i][j] = fmaf(a[i].z, bk.z, accK[i][j]);
          accK[i][j] = fmaf(a[i].w, bk.w, accK[i][j]);
          accV[i][j] = fmaf(a[i].x, bv.x, accV[i][j]);
          accV[i][j] = fmaf(a[i].y, bv.y, accV[i][j]);
          accV[i][j] = fmaf(a[i].z, bv.z, accV[i][j]);
          accV[i][j] = fmaf(a[i].w, bv.w, accV[i][j]);
        }
      }
    }
    #pragma unroll
    for (int i = 0; i < 4; ++i) {
      int r = rowBase + ty * 4 + i;
      f32x4 vk = {accK[i][0], accK[i][1], accK[i][2], accK[i][3]};
      f32x4 vv = {accV[i][0], accV[i][1], accV[i][2], accV[i][3]};
      *(f32x4*)&kf[r * 256 + c0] = vk;
      *(f32x4*)&vout[r * 256 + c0] = vv;
      ushort4 hk;
      hk.x = f2bf(accK[i][0]); hk.y = f2bf(accK[i][1]);
      hk.z = f2bf(accK[i][2]); hk.w = f2bf(accK[i][3]);
      *(ushort4*)&kh[r * 256 + c0] = hk;
    }
  }
}

// ---------------- K2: logit = qh @ kh^T (bf16 MFMA) + fused blockmax ----------------
// Round-10 proven structure verbatim (regular cached stores).
__global__ __launch_bounds__(256) void logit_gemm(
    const unsigned short* __restrict__ qh, const unsigned short* __restrict__ kh,
    float* __restrict__ out, float* __restrict__ pmax)
{
  __shared__ short AsBuf[2][128 * 32];
  __shared__ short BsBuf[2][128 * 32];
  __shared__ float Pm[128][2];
  const int t = threadIdx.x;
  const int bid = blockIdx.x;
  const int wg = (bid & 7) * 512 + (bid >> 3);  // XCD-chunked swizzle (4096 % 8 == 0)
  const int aRow0 = (wg >> 5) * 128;            // M block
  const int bRow0 = (wg & 31) * 128;            // N block
  const int lane = t & 63, wid = t >> 6;
  const int wr = wid >> 1, wc = wid & 1;
  f32x4 acc[4][4];
  #pragma unroll
  for (int m = 0; m < 4; ++m)
    #pragma unroll
    for (int n = 0; n < 4; ++n) { acc[m][n].x = 0.f; acc[m][n].y = 0.f; acc[m][n].z = 0.f; acc[m][n].w = 0.f; }

  const short* qs = (const short*)qh;
  const short* ks = (const short*)kh;

  #define STAGE32(AB, BB, KT) do {                                          \
    _Pragma("unroll")                                                       \
    for (int ci = 0; ci < 2; ++ci) {                                        \
      int c = ci * 256 + t;                                                 \
      int row = c >> 2;                                                     \
      int slot = (c & 3) ^ (row & 3);                                       \
      int koff = (KT) * 32 + slot * 8;                                      \
      load_lds16(qs + (size_t)(aRow0 + row) * 256 + koff, (AB) + c * 8);    \
      load_lds16(ks + (size_t)(bRow0 + row) * 256 + koff, (BB) + c * 8);    \
    } } while (0)

  STAGE32(AsBuf[0], BsBuf[0], 0);
  #pragma unroll
  for (int kt = 0; kt < 8; ++kt) {
    const int buf = kt & 1;
    __syncthreads();                       // drains buf's loads; fences prev reads of buf^1
    if (kt < 7) STAGE32(AsBuf[buf ^ 1], BsBuf[buf ^ 1], kt + 1);
    const short* As = AsBuf[buf];
    const short* Bs = BsBuf[buf];
    s16x8 af[4], bfr[4];
    #pragma unroll
    for (int m = 0; m < 4; ++m) {
      int row = wr * 64 + m * 16 + (lane & 15);
      int slot = (lane >> 4) ^ (row & 3);
      af[m] = *(const s16x8*)(As + row * 32 + slot * 8);
    }
    #pragma unroll
    for (int n = 0; n < 4; ++n) {
      int row = wc * 64 + n * 16 + (lane & 15);
      int slot = (lane >> 4) ^ (row & 3);
      bfr[n] = *(const s16x8*)(Bs + row * 32 + slot * 8);
    }
    #pragma unroll
    for (int m = 0; m < 4; ++m)
      #pragma unroll
      for (int n = 0; n < 4; ++n)
        acc[m][n] = __builtin_amdgcn_mfma_f32_16x16x32_bf16(af[m], bfr[n], acc[m][n], 0, 0, 0);
  }
  #undef STAGE32

  // fused blockmax: per (row, this 128-col block) max, into Pm then pmax
  #pragma unroll
  for (int m = 0; m < 4; ++m)
    #pragma unroll
    for (int j = 0; j < 4; ++j) {
      float bm = fmaxf(fmaxf(acc[m][0][j], acc[m][1][j]),
                       fmaxf(acc[m][2][j], acc[m][3][j]));
      #pragma unroll
      for (int off = 1; off < 16; off <<= 1) bm = fmaxf(bm, __shfl_xor(bm, off));
      if ((lane & 15) == 0) Pm[wr * 64 + m * 16 + (lane >> 4) * 4 + j][wc] = bm;
    }
  // logit store (proven scalar epilogue — L2 merges the 64B segments)
  const int colLane = lane & 15, rowQuad = (lane >> 4) * 4;
  #pragma unroll
  for (int m = 0; m < 4; ++m)
    #pragma unroll
    for (int n = 0; n < 4; ++n) {
      int row = aRow0 + wr * 64 + m * 16 + rowQuad;
      int col = bRow0 + wc * 64 + n * 16 + colLane;
      #pragma unroll
      for (int j = 0; j < 4; ++j)
        out[(size_t)(row + j) * 4096 + col] = acc[m][n][j];
    }
  __syncthreads();
  if (t < 128) pmax[(size_t)(aRow0 + t) * 32 + (bRow0 >> 7)] = fmaxf(Pm[t][0], Pm[t][1]);
}

// ---------------- K3: finalize — single-candidate fast path + exact recheck fallback ----------------
__global__ __launch_bounds__(1024) void finalize_kernel(
    const float* __restrict__ logit, const float* __restrict__ pmax,
    const float* __restrict__ qf, const float* __restrict__ kf,
    const float* __restrict__ vout, float* __restrict__ quant, float* __restrict__ code)
{
  __shared__ __align__(16) float Vs[32][260];
  __shared__ int idxArr[32];
  const int t = threadIdx.x, wave = t >> 6, lane = t & 63;
  const int nh = blockIdx.x, n = nh >> 5, h = nh & 31;
  for (int ri = 0; ri < 2; ++ri) {
    const int w = wave * 2 + ri;
    const size_t r = (size_t)nh * 32 + w;
    float pv = -3e38f;
    if (lane < 32) pv = pmax[r * 32 + lane];
    float gmax = pv;
    #pragma unroll
    for (int off = 32; off; off >>= 1) gmax = fmaxf(gmax, __shfl_xor(gmax, off));
    const float thr = gmax - ARGMAX_MARGIN;
    const unsigned long long bmAll = __ballot(pv >= thr);  // candidate 128-col blocks
    // pass 1: count candidate columns, record the first one
    int tot = 0, firstJ = 0x7fffffff;
    {
      unsigned long long bm = bmAll;
      #pragma unroll 1
      while (bm) {
        const int nb = __ffsll(bm) - 1; bm &= bm - 1;
        const float2 lv = *(const float2*)&logit[r * 4096 + nb * 128 + lane * 2];
        unsigned long long c0 = __ballot(lv.x >= thr);
        unsigned long long c1 = __ballot(lv.y >= thr);
        tot += __popcll(c0) + __popcll(c1);
        if (firstJ == 0x7fffffff && (c0 | c1)) {
          int j0 = c0 ? nb * 128 + 2 * (__ffsll(c0) - 1)     : 0x7fffffff;
          int j1 = c1 ? nb * 128 + 2 * (__ffsll(c1) - 1) + 1 : 0x7fffffff;
          firstJ = j0 < j1 ? j0 : j1;
        }
      }
    }
    int bestJ = firstJ;
    if (tot > 1) {     // slow path: exact f64 recheck of every candidate
      const f32x4 qv = ((const f32x4*)(qf + r * 256))[lane];
      float bestV = -3e38f; bestJ = 0x7fffffff;
      unsigned long long bm = bmAll;
      #pragma unroll 1
      while (bm) {
        const int nb = __ffsll(bm) - 1; bm &= bm - 1;
        const float2 lv = *(const float2*)&logit[r * 4096 + nb * 128 + lane * 2];
        unsigned long long c0 = __ballot(lv.x >= thr);
        unsigned long long c1 = __ballot(lv.y >= thr);
        #pragma unroll 1
        for (int half = 0; half < 2; ++half) {
          unsigned long long mm = half ? c1 : c0;
          #pragma unroll 1
          while (mm) {
            const int L = __ffsll(mm) - 1; mm &= mm - 1;
            const int j = nb * 128 + L * 2 + half;
            const f32x4 kv = ((const f32x4*)(kf + (size_t)j * 256))[lane];
            double s = (double)qv.x * kv.x + (double)qv.y * kv.y
                     + (double)qv.z * kv.z + (double)qv.w * kv.w;
            #pragma unroll
            for (int off = 32; off; off >>= 1) s += __shfl_xor(s, off);
            const float val = (float)(s * 0.0625);
            if (val > bestV || (val == bestV && j < bestJ)) { bestV = val; bestJ = j; }
          }
        }
      }
    }
    if (lane == 0) idxArr[w] = bestJ;
  }
  __syncthreads();
  // stage the 32 selected v-rows in LDS (coalesced reads)
  for (int ri = 0; ri < 2; ++ri) {
    const int w2 = wave * 2 + ri;
    const int idx = idxArr[w2];
    const f32x4 vv = ((const f32x4*)(vout + (size_t)idx * 256))[lane];
    *(f32x4*)&Vs[w2][lane * 4] = vv;
  }
  __syncthreads();
  // transposed write: quant[n][c][h][w], w contiguous
  const int wcol = t & 31, cg = t >> 5;
  #pragma unroll
  for (int cc = 0; cc < 8; ++cc) {
    const int c = cg * 8 + cc;
    quant[(((size_t)n * 256 + c) * 32 + h) * 32 + wcol] = Vs[wcol][c];
  }
  if (t < 32) code[nh * 32 + t] = (float)(idxArr[t] & 255);
}

extern "C" void kernel_launch(void* const* d_in, const int* in_sizes, int n_in,
                              void* d_out, int out_size, void* d_ws, size_t ws_size,
                              hipStream_t stream) {
  (void)in_sizes; (void)n_in; (void)out_size; (void)ws_size;
  const float* latent = (const float*)d_in[0];
  const float* cb     = (const float*)d_in[1];
  const float* wq     = (const float*)d_in[2];
  const float* wk     = (const float*)d_in[3];
  const float* wv     = (const float*)d_in[4];

  float* out   = (float*)d_out;
  float* quant = out + QUANT_OFF;
  float* code  = out + CODE_OFF;
  float* logit = out + LOGIT_OFF;
  float* vout  = out + V_OFF;

  char* ws = (char*)d_ws;
  float*          qf   = (float*)(ws + 0);                 // 16 MB
  float*          kf   = (float*)(ws + 16777216);          // 4 MB
  unsigned short* qh   = (unsigned short*)(ws + 20971520); // 8 MB
  unsigned short* kh   = (unsigned short*)(ws + 29360128); // 2 MB
  float*          pmax = (float*)(ws + 31457280);          // 2 MB (16384 x 32), ends at 32 MB

  kvq_kernel<<<1280, 256, 0, stream>>>(latent, wq, cb, wk, wv, qf, qh, kf, kh, vout);
  logit_gemm<<<4096, 256, 0, stream>>>(qh, kh, logit, pmax);
  finalize_kernel<<<512, 1024, 0, stream>>>(logit, pmax, qf, kf, vout, quant, code);
}

// Round 14
// 175.324 us; speedup vs baseline: 1.8327x; 1.6847x over previous
//
#include <hip/hip_runtime.h>
#include <stdint.h>

typedef float f32x4 __attribute__((ext_vector_type(4)));
typedef short s16x8 __attribute__((ext_vector_type(8)));

// N=16, C=256, H=32, W=32, K=4096, M = N*H*W = 16384
// d_out layout (floats): quant[4194304] | code[16384] | logit[67108864] | v[1048576]
#define QUANT_OFF 0
#define CODE_OFF  4194304
#define LOGIT_OFF 4210688
#define V_OFF     71319552

// logit std ~= 0.0625 (codebook prescaled by 1/sqrt(C)); bf16-path absmax err 0.00195.
// Margin must exceed 2*err (0.0039); use 1/128 for 2x headroom.
#define ARGMAX_MARGIN 0.0078125f

__device__ __forceinline__ unsigned short f2bf(float f) {
  unsigned int u = __float_as_uint(f);
  u = u + 0x7fffu + ((u >> 16) & 1u);   // RNE
  return (unsigned short)(u >> 16);
}

__device__ __forceinline__ void load_lds16(const void* g, void* l) {
  __builtin_amdgcn_global_load_lds(
      (const __attribute__((address_space(1))) unsigned int*)g,
      (__attribute__((address_space(3))) unsigned int*)l, 16, 0, 0);
}

// ---------------- K1: fp32 VALU GEMMs, two-tile LDS structure ----------------
// blocks 0..255: k/v = cb@{wk,wv}^T (64-row x 64-col tiles, B restaged per half)
// blocks 256..1279: q = x@wq^T
// BM=BN=BK=64; As/Bs [64][68] f32 (34.8 KB -> 4 blocks/CU). Step-16 output map:
// thread (tx,ty) owns rows {ty+16i}, cols {tx+16j} -> conflict-free f32x4 LDS reads.
__global__ __launch_bounds__(256) void kvq_kernel(
    const float* __restrict__ latent, const float* __restrict__ wq,
    const float* __restrict__ cb, const float* __restrict__ wk, const float* __restrict__ wv,
    float* __restrict__ qf, unsigned short* __restrict__ qh,
    float* __restrict__ kf, unsigned short* __restrict__ kh, float* __restrict__ vout)
{
  __shared__ __align__(16) float As[64][68];
  __shared__ __align__(16) float Bs[64][68];
  const int t = threadIdx.x;
  const int bid = blockIdx.x;
  const int tx = t & 15, ty = (t >> 4) & 3;   // 16 x 4 (x4 replicated over waves? no: t>>4 in 0..15)
  // NOTE: 256 threads = (tx 0..15) x (tyFull 0..15); split tyFull into ty(0..3) x ts(0..3):
  const int tyFull = t >> 4;                  // 0..15
  const int tyq = tyFull & 3;                 // row lane 0..3
  const int tsq = tyFull >> 2;                // row super 0..3 -> rows tsq*... unused; use 4x4 grid below
  (void)ty; (void)tyq; (void)tsq;

  // Use a 16x16 thread grid: rows handled by ry (t>>4), cols by tx. Each thread:
  // rows {ry + 16i}? ry in 0..15 and i in 0..3 gives 64 rows ✓, cols {tx + 16j} ✓.
  const int ry = t >> 4;  // 0..15

  if (bid >= 256) {
    // ---------------- q path ----------------
    const int qb = bid - 256;
    const int rowBase = (qb & 255) * 64;
    const int colBase = (qb >> 8) * 64;
    const int n = rowBase >> 10;
    const int hw0 = rowBase & 1023;
    const f32x4* lat4 = (const f32x4*)latent;
    const f32x4* wq4 = (const f32x4*)wq;
    float acc[4][4] = {{0.f}};
    for (int kt = 0; kt < 4; ++kt) {
      __syncthreads();
      // stage As[row][k]: transpose from latent (hw-contiguous)
      #pragma unroll
      for (int it = 0; it < 4; ++it) {
        int c = it * 256 + t;
        int kk = c >> 4, rq = c & 15;
        f32x4 vv = lat4[(size_t)(n * 256 + kt * 64 + kk) * 256 + (hw0 >> 2) + rq];
        As[rq * 4 + 0][kk] = vv.x;
        As[rq * 4 + 1][kk] = vv.y;
        As[rq * 4 + 2][kk] = vv.z;
        As[rq * 4 + 3][kk] = vv.w;
      }
      // stage Bs[col][k]: direct from wq (k-contiguous rows)
      #pragma unroll
      for (int it = 0; it < 4; ++it) {
        int c = it * 256 + t;
        int col = c >> 4, kq4 = c & 15;
        f32x4 vv = wq4[(size_t)(colBase + col) * 64 + kt * 16 + kq4];
        *(f32x4*)&Bs[col][kq4 * 4] = vv;
      }
      __syncthreads();
      #pragma unroll
      for (int kc = 0; kc < 16; ++kc) {
        f32x4 a[4], b[4];
        #pragma unroll
        for (int i = 0; i < 4; ++i) a[i] = *(const f32x4*)&As[ry + 16 * i][kc * 4];
        #pragma unroll
        for (int j = 0; j < 4; ++j) b[j] = *(const f32x4*)&Bs[tx + 16 * j][kc * 4];
        #pragma unroll
        for (int i = 0; i < 4; ++i)
          #pragma unroll
          for (int j = 0; j < 4; ++j) {
            acc[i][j] = fmaf(a[i].x, b[j].x, acc[i][j]);
            acc[i][j] = fmaf(a[i].y, b[j].y, acc[i][j]);
            acc[i][j] = fmaf(a[i].z, b[j].z, acc[i][j]);
            acc[i][j] = fmaf(a[i].w, b[j].w, acc[i][j]);
          }
      }
    }
    #pragma unroll
    for (int i = 0; i < 4; ++i) {
      const int r = rowBase + ry + 16 * i;
      #pragma unroll
      for (int j = 0; j < 4; ++j) {
        const int c = colBase + tx + 16 * j;
        qf[(size_t)r * 256 + c] = acc[i][j];
        qh[(size_t)r * 256 + c] = f2bf(acc[i][j] * 0.0625f);
      }
    }
  } else {
    // ---------------- k/v path ----------------
    const int rowBase = (bid & 63) * 64;
    const int colBase = (bid >> 6) * 64;
    const f32x4* cb4 = (const f32x4*)cb;
    const f32x4* wk4 = (const f32x4*)wk;
    const f32x4* wv4 = (const f32x4*)wv;
    float accK[4][4] = {{0.f}}, accV[4][4] = {{0.f}};
    for (int kt = 0; kt < 4; ++kt) {
      __syncthreads();
      // stage As[row][k]: direct from cb (k-contiguous rows)
      #pragma unroll
      for (int it = 0; it < 4; ++it) {
        int c = it * 256 + t;
        int row = c >> 4, kq4 = c & 15;
        f32x4 vv = cb4[(size_t)(rowBase + row) * 64 + kt * 16 + kq4];
        *(f32x4*)&As[row][kq4 * 4] = vv;
      }
      // stage Bs = wk tile
      #pragma unroll
      for (int it = 0; it < 4; ++it) {
        int c = it * 256 + t;
        int col = c >> 4, kq4 = c & 15;
        f32x4 vv = wk4[(size_t)(colBase + col) * 64 + kt * 16 + kq4];
        *(f32x4*)&Bs[col][kq4 * 4] = vv;
      }
      __syncthreads();
      #pragma unroll
      for (int kc = 0; kc < 16; ++kc) {
        f32x4 a[4], b[4];
        #pragma unroll
        for (int i = 0; i < 4; ++i) a[i] = *(const f32x4*)&As[ry + 16 * i][kc * 4];
        #pragma unroll
        for (int j = 0; j < 4; ++j) b[j] = *(const f32x4*)&Bs[tx + 16 * j][kc * 4];
        #pragma unroll
        for (int i = 0; i < 4; ++i)
          #pragma unroll
          for (int j = 0; j < 4; ++j) {
            accK[i][j] = fmaf(a[i].x, b[j].x, accK[i][j]);
            accK[i][j] = fmaf(a[i].y, b[j].y, accK[i][j]);
            accK[i][j] = fmaf(a[i].z, b[j].z, accK[i][j]);
            accK[i][j] = fmaf(a[i].w, b[j].w, accK[i][j]);
          }
      }
      __syncthreads();
      // restage Bs = wv tile (As stays)
      #pragma unroll
      for (int it = 0; it < 4; ++it) {
        int c = it * 256 + t;
        int col = c >> 4, kq4 = c & 15;
        f32x4 vv = wv4[(size_t)(colBase + col) * 64 + kt * 16 + kq4];
        *(f32x4*)&Bs[col][kq4 * 4] = vv;
      }
      __syncthreads();
      #pragma unroll
      for (int kc = 0; kc < 16; ++kc) {
        f32x4 a[4], b[4];
        #pragma unroll
        for (int i = 0; i < 4; ++i) a[i] = *(const f32x4*)&As[ry + 16 * i][kc * 4];
        #pragma unroll
        for (int j = 0; j < 4; ++j) b[j] = *(const f32x4*)&Bs[tx + 16 * j][kc * 4];
        #pragma unroll
        for (int i = 0; i < 4; ++i)
          #pragma unroll
          for (int j = 0; j < 4; ++j) {
            accV[i][j] = fmaf(a[i].x, b[j].x, accV[i][j]);
            accV[i][j] = fmaf(a[i].y, b[j].y, accV[i][j]);
            accV[i][j] = fmaf(a[i].z, b[j].z, accV[i][j]);
            accV[i][j] = fmaf(a[i].w, b[j].w, accV[i][j]);
          }
      }
    }
    #pragma unroll
    for (int i = 0; i < 4; ++i) {
      const int r = rowBase + ry + 16 * i;
      #pragma unroll
      for (int j = 0; j < 4; ++j) {
        const int c = colBase + tx + 16 * j;
        kf[(size_t)r * 256 + c] = accK[i][j];
        kh[(size_t)r * 256 + c] = f2bf(accK[i][j]);
        vout[(size_t)r * 256 + c] = accV[i][j];
      }
    }
  }
}

// ---------------- K2: logit = qh @ kh^T (bf16 MFMA) + fused blockmax ----------------
// Round-10 proven structure verbatim.
__global__ __launch_bounds__(256) void logit_gemm(
    const unsigned short* __restrict__ qh, const unsigned short* __restrict__ kh,
    float* __restrict__ out, float* __restrict__ pmax)
{
  __shared__ short AsBuf[2][128 * 32];
  __shared__ short BsBuf[2][128 * 32];
  __shared__ float Pm[128][2];
  const int t = threadIdx.x;
  const int bid = blockIdx.x;
  const int wg = (bid & 7) * 512 + (bid >> 3);  // XCD-chunked swizzle (4096 % 8 == 0)
  const int aRow0 = (wg >> 5) * 128;            // M block
  const int bRow0 = (wg & 31) * 128;            // N block
  const int lane = t & 63, wid = t >> 6;
  const int wr = wid >> 1, wc = wid & 1;
  f32x4 acc[4][4];
  #pragma unroll
  for (int m = 0; m < 4; ++m)
    #pragma unroll
    for (int n = 0; n < 4; ++n) { acc[m][n].x = 0.f; acc[m][n].y = 0.f; acc[m][n].z = 0.f; acc[m][n].w = 0.f; }

  const short* qs = (const short*)qh;
  const short* ks = (const short*)kh;

  #define STAGE32(AB, BB, KT) do {                                          \
    _Pragma("unroll")                                                       \
    for (int ci = 0; ci < 2; ++ci) {                                        \
      int c = ci * 256 + t;                                                 \
      int row = c >> 2;                                                     \
      int slot = (c & 3) ^ (row & 3);                                       \
      int koff = (KT) * 32 + slot * 8;                                      \
      load_lds16(qs + (size_t)(aRow0 + row) * 256 + koff, (AB) + c * 8);    \
      load_lds16(ks + (size_t)(bRow0 + row) * 256 + koff, (BB) + c * 8);    \
    } } while (0)

  STAGE32(AsBuf[0], BsBuf[0], 0);
  #pragma unroll
  for (int kt = 0; kt < 8; ++kt) {
    const int buf = kt & 1;
    __syncthreads();                       // drains buf's loads; fences prev reads of buf^1
    if (kt < 7) STAGE32(AsBuf[buf ^ 1], BsBuf[buf ^ 1], kt + 1);
    const short* As = AsBuf[buf];
    const short* Bs = BsBuf[buf];
    s16x8 af[4], bfr[4];
    #pragma unroll
    for (int m = 0; m < 4; ++m) {
      int row = wr * 64 + m * 16 + (lane & 15);
      int slot = (lane >> 4) ^ (row & 3);
      af[m] = *(const s16x8*)(As + row * 32 + slot * 8);
    }
    #pragma unroll
    for (int n = 0; n < 4; ++n) {
      int row = wc * 64 + n * 16 + (lane & 15);
      int slot = (lane >> 4) ^ (row & 3);
      bfr[n] = *(const s16x8*)(Bs + row * 32 + slot * 8);
    }
    #pragma unroll
    for (int m = 0; m < 4; ++m)
      #pragma unroll
      for (int n = 0; n < 4; ++n)
        acc[m][n] = __builtin_amdgcn_mfma_f32_16x16x32_bf16(af[m], bfr[n], acc[m][n], 0, 0, 0);
  }
  #undef STAGE32

  // fused blockmax: per (row, this 128-col block) max, into Pm then pmax
  #pragma unroll
  for (int m = 0; m < 4; ++m)
    #pragma unroll
    for (int j = 0; j < 4; ++j) {
      float bm = fmaxf(fmaxf(acc[m][0][j], acc[m][1][j]),
                       fmaxf(acc[m][2][j], acc[m][3][j]));
      #pragma unroll
      for (int off = 1; off < 16; off <<= 1) bm = fmaxf(bm, __shfl_xor(bm, off));
      if ((lane & 15) == 0) Pm[wr * 64 + m * 16 + (lane >> 4) * 4 + j][wc] = bm;
    }
  // logit store (proven scalar epilogue — L2 merges the 64B segments)
  const int colLane = lane & 15, rowQuad = (lane >> 4) * 4;
  #pragma unroll
  for (int m = 0; m < 4; ++m)
    #pragma unroll
    for (int n = 0; n < 4; ++n) {
      int row = aRow0 + wr * 64 + m * 16 + rowQuad;
      int col = bRow0 + wc * 64 + n * 16 + colLane;
      #pragma unroll
      for (int j = 0; j < 4; ++j)
        out[(size_t)(row + j) * 4096 + col] = acc[m][n][j];
    }
  __syncthreads();
  if (t < 128) pmax[(size_t)(aRow0 + t) * 32 + (bRow0 >> 7)] = fmaxf(Pm[t][0], Pm[t][1]);
}

// ---------------- K3: finalize — single-candidate fast path + exact recheck fallback ----------------
__global__ __launch_bounds__(1024) void finalize_kernel(
    const float* __restrict__ logit, const float* __restrict__ pmax,
    const float* __restrict__ qf, const float* __restrict__ kf,
    const float* __restrict__ vout, float* __restrict__ quant, float* __restrict__ code)
{
  __shared__ __align__(16) float Vs[32][260];
  __shared__ int idxArr[32];
  const int t = threadIdx.x, wave = t >> 6, lane = t & 63;
  const int nh = blockIdx.x, n = nh >> 5, h = nh & 31;
  for (int ri = 0; ri < 2; ++ri) {
    const int w = wave * 2 + ri;
    const size_t r = (size_t)nh * 32 + w;
    float pv = -3e38f;
    if (lane < 32) pv = pmax[r * 32 + lane];
    float gmax = pv;
    #pragma unroll
    for (int off = 32; off; off >>= 1) gmax = fmaxf(gmax, __shfl_xor(gmax, off));
    const float thr = gmax - ARGMAX_MARGIN;
    const unsigned long long bmAll = __ballot(pv >= thr);  // candidate 128-col blocks
    int tot = 0, firstJ = 0x7fffffff;
    {
      unsigned long long bm = bmAll;
      #pragma unroll 1
      while (bm) {
        const int nb = __ffsll(bm) - 1; bm &= bm - 1;
        const float2 lv = *(const float2*)&logit[r * 4096 + nb * 128 + lane * 2];
        unsigned long long c0 = __ballot(lv.x >= thr);
        unsigned long long c1 = __ballot(lv.y >= thr);
        tot += __popcll(c0) + __popcll(c1);
        if (firstJ == 0x7fffffff && (c0 | c1)) {
          int j0 = c0 ? nb * 128 + 2 * (__ffsll(c0) - 1)     : 0x7fffffff;
          int j1 = c1 ? nb * 128 + 2 * (__ffsll(c1) - 1) + 1 : 0x7fffffff;
          firstJ = j0 < j1 ? j0 : j1;
        }
      }
    }
    int bestJ = firstJ;
    if (tot > 1) {     // slow path: exact f64 recheck of every candidate
      const f32x4 qv = ((const f32x4*)(qf + r * 256))[lane];
      float bestV = -3e38f; bestJ = 0x7fffffff;
      unsigned long long bm = bmAll;
      #pragma unroll 1
      while (bm) {
        const int nb = __ffsll(bm) - 1; bm &= bm - 1;
        const float2 lv = *(const float2*)&logit[r * 4096 + nb * 128 + lane * 2];
        unsigned long long c0 = __ballot(lv.x >= thr);
        unsigned long long c1 = __ballot(lv.y >= thr);
        #pragma unroll 1
        for (int half = 0; half < 2; ++half) {
          unsigned long long mm = half ? c1 : c0;
          #pragma unroll 1
          while (mm) {
            const int L = __ffsll(mm) - 1; mm &= mm - 1;
            const int j = nb * 128 + L * 2 + half;
            const f32x4 kv = ((const f32x4*)(kf + (size_t)j * 256))[lane];
            double s = (double)qv.x * kv.x + (double)qv.y * kv.y
                     + (double)qv.z * kv.z + (double)qv.w * kv.w;
            #pragma unroll
            for (int off = 32; off; off >>= 1) s += __shfl_xor(s, off);
            const float val = (float)(s * 0.0625);
            if (val > bestV || (val == bestV && j < bestJ)) { bestV = val; bestJ = j; }
          }
        }
      }
    }
    if (lane == 0) idxArr[w] = bestJ;
  }
  __syncthreads();
  for (int ri = 0; ri < 2; ++ri) {
    const int w2 = wave * 2 + ri;
    const int idx = idxArr[w2];
    const f32x4 vv = ((const f32x4*)(vout + (size_t)idx * 256))[lane];
    *(f32x4*)&Vs[w2][lane * 4] = vv;
  }
  __syncthreads();
  const int wcol = t & 31, cg = t >> 5;
  #pragma unroll
  for (int cc = 0; cc < 8; ++cc) {
    const int c = cg * 8 + cc;
    quant[(((size_t)n * 256 + c) * 32 + h) * 32 + wcol] = Vs[wcol][c];
  }
  if (t < 32) code[nh * 32 + t] = (float)(idxArr[t] & 255);
}

extern "C" void kernel_launch(void* const* d_in, const int* in_sizes, int n_in,
                              void* d_out, int out_size, void* d_ws, size_t ws_size,
                              hipStream_t stream) {
  (void)in_sizes; (void)n_in; (void)out_size; (void)ws_size;
  const float* latent = (const float*)d_in[0];
  const float* cb     = (const float*)d_in[1];
  const float* wq     = (const float*)d_in[2];
  const float* wk     = (const float*)d_in[3];
  const float* wv     = (const float*)d_in[4];

  float* out   = (float*)d_out;
  float* quant = out + QUANT_OFF;
  float* code  = out + CODE_OFF;
  float* logit = out + LOGIT_OFF;
  float* vout  = out + V_OFF;

  char* ws = (char*)d_ws;
  float*          qf   = (float*)(ws + 0);                 // 16 MB
  float*          kf   = (float*)(ws + 16777216);          // 4 MB
  unsigned short* qh   = (unsigned short*)(ws + 20971520); // 8 MB
  unsigned short* kh   = (unsigned short*)(ws + 29360128); // 2 MB
  float*          pmax = (float*)(ws + 31457280);          // 2 MB (16384 x 32), ends at 32 MB

  kvq_kernel<<<1280, 256, 0, stream>>>(latent, wq, cb, wk, wv, qf, qh, kf, kh, vout);
  logit_gemm<<<4096, 256, 0, stream>>>(qh, kh, logit, pmax);
  finalize_kernel<<<512, 1024, 0, stream>>>(logit, pmax, qf, kf, vout, quant, code);
}

// Round 15
// 170.433 us; speedup vs baseline: 1.8853x; 1.0287x over previous
//
#include <hip/hip_runtime.h>
#include <stdint.h>

typedef float f32x4 __attribute__((ext_vector_type(4)));
typedef short s16x8 __attribute__((ext_vector_type(8)));

// N=16, C=256, H=32, W=32, K=4096, M = N*H*W = 16384
// d_out layout (floats): quant[4194304] | code[16384] | logit[67108864] | v[1048576]
#define QUANT_OFF 0
#define CODE_OFF  4194304
#define LOGIT_OFF 4210688
#define V_OFF     71319552

// logit std ~= 0.0625 (codebook prescaled by 1/sqrt(C)); bf16-path absmax err 0.00195.
// Margin must exceed 2*err (0.0039); use 1/128 for 2x headroom.
#define ARGMAX_MARGIN 0.0078125f

__device__ __forceinline__ unsigned short f2bf(float f) {
  unsigned int u = __float_as_uint(f);
  u = u + 0x7fffu + ((u >> 16) & 1u);   // RNE
  return (unsigned short)(u >> 16);
}

__device__ __forceinline__ void load_lds16(const void* g, void* l) {
  __builtin_amdgcn_global_load_lds(
      (const __attribute__((address_space(1))) unsigned int*)g,
      (__attribute__((address_space(3))) unsigned int*)l, 16, 0, 0);
}

// ---------------- K1: fp32 VALU GEMMs, two-tile LDS structure ----------------
// blocks 0..255: k/v = cb@{wk,wv}^T.  blocks 256..1279: q = x@wq^T.
// q path: AsT[k][row] staging — latent's f32x4 (4 consecutive hw = 4 rows, one k)
// stores directly, conflict-free, no transpose. Thread tile: rows ry*4..+3,
// cols tx+16j. kv path: As[row][k] direct staging (cb is k-contiguous).
__global__ __launch_bounds__(256) void kvq_kernel(
    const float* __restrict__ latent, const float* __restrict__ wq,
    const float* __restrict__ cb, const float* __restrict__ wk, const float* __restrict__ wv,
    float* __restrict__ qf, unsigned short* __restrict__ qh,
    float* __restrict__ kf, unsigned short* __restrict__ kh, float* __restrict__ vout)
{
  __shared__ __align__(16) float As[64][68];   // q path: [k][row]; kv path: [row][k]
  __shared__ __align__(16) float Bs[64][68];   // both: [col][k]
  const int t = threadIdx.x;
  const int bid = blockIdx.x;
  const int tx = t & 15;
  const int ry = t >> 4;  // 0..15

  if (bid >= 256) {
    // ---------------- q path ----------------
    const int qb = bid - 256;
    const int rowBase = (qb & 255) * 64;
    const int colBase = (qb >> 8) * 64;
    const int n = rowBase >> 10;
    const int hw0 = rowBase & 1023;
    const f32x4* lat4 = (const f32x4*)latent;
    const f32x4* wq4 = (const f32x4*)wq;
    float acc[4][4] = {{0.f}};
    for (int kt = 0; kt < 4; ++kt) {
      __syncthreads();
      // stage AsT[k][row]: direct f32x4, conflict-free (no transpose needed)
      #pragma unroll
      for (int it = 0; it < 4; ++it) {
        int c = it * 256 + t;
        int kk = c >> 4, rq = c & 15;
        f32x4 vv = lat4[(size_t)(n * 256 + kt * 64 + kk) * 256 + (hw0 >> 2) + rq];
        *(f32x4*)&As[kk][rq * 4] = vv;
      }
      // stage Bs[col][k]: direct from wq (k-contiguous rows)
      #pragma unroll
      for (int it = 0; it < 4; ++it) {
        int c = it * 256 + t;
        int col = c >> 4, kq4 = c & 15;
        f32x4 vv = wq4[(size_t)(colBase + col) * 64 + kt * 16 + kq4];
        *(f32x4*)&Bs[col][kq4 * 4] = vv;
      }
      __syncthreads();
      #pragma unroll
      for (int kc = 0; kc < 16; ++kc) {
        f32x4 a[4], b[4];
        #pragma unroll
        for (int c = 0; c < 4; ++c) a[c] = *(const f32x4*)&As[kc * 4 + c][ry * 4];  // 4 rows @ k
        #pragma unroll
        for (int j = 0; j < 4; ++j) b[j] = *(const f32x4*)&Bs[tx + 16 * j][kc * 4]; // 4 ks @ col
        #pragma unroll
        for (int i = 0; i < 4; ++i)
          #pragma unroll
          for (int j = 0; j < 4; ++j) {
            acc[i][j] = fmaf(a[0][i], b[j].x, acc[i][j]);
            acc[i][j] = fmaf(a[1][i], b[j].y, acc[i][j]);
            acc[i][j] = fmaf(a[2][i], b[j].z, acc[i][j]);
            acc[i][j] = fmaf(a[3][i], b[j].w, acc[i][j]);
          }
      }
    }
    #pragma unroll
    for (int i = 0; i < 4; ++i) {
      const int r = rowBase + ry * 4 + i;
      #pragma unroll
      for (int j = 0; j < 4; ++j) {
        const int c = colBase + tx + 16 * j;
        qf[(size_t)r * 256 + c] = acc[i][j];
        qh[(size_t)r * 256 + c] = f2bf(acc[i][j] * 0.0625f);
      }
    }
  } else {
    // ---------------- k/v path (round-14 verbatim) ----------------
    const int rowBase = (bid & 63) * 64;
    const int colBase = (bid >> 6) * 64;
    const f32x4* cb4 = (const f32x4*)cb;
    const f32x4* wk4 = (const f32x4*)wk;
    const f32x4* wv4 = (const f32x4*)wv;
    float accK[4][4] = {{0.f}}, accV[4][4] = {{0.f}};
    for (int kt = 0; kt < 4; ++kt) {
      __syncthreads();
      #pragma unroll
      for (int it = 0; it < 4; ++it) {
        int c = it * 256 + t;
        int row = c >> 4, kq4 = c & 15;
        f32x4 vv = cb4[(size_t)(rowBase + row) * 64 + kt * 16 + kq4];
        *(f32x4*)&As[row][kq4 * 4] = vv;
      }
      #pragma unroll
      for (int it = 0; it < 4; ++it) {
        int c = it * 256 + t;
        int col = c >> 4, kq4 = c & 15;
        f32x4 vv = wk4[(size_t)(colBase + col) * 64 + kt * 16 + kq4];
        *(f32x4*)&Bs[col][kq4 * 4] = vv;
      }
      __syncthreads();
      #pragma unroll
      for (int kc = 0; kc < 16; ++kc) {
        f32x4 a[4], b[4];
        #pragma unroll
        for (int i = 0; i < 4; ++i) a[i] = *(const f32x4*)&As[ry + 16 * i][kc * 4];
        #pragma unroll
        for (int j = 0; j < 4; ++j) b[j] = *(const f32x4*)&Bs[tx + 16 * j][kc * 4];
        #pragma unroll
        for (int i = 0; i < 4; ++i)
          #pragma unroll
          for (int j = 0; j < 4; ++j) {
            accK[i][j] = fmaf(a[i].x, b[j].x, accK[i][j]);
            accK[i][j] = fmaf(a[i].y, b[j].y, accK[i][j]);
            accK[i][j] = fmaf(a[i].z, b[j].z, accK[i][j]);
            accK[i][j] = fmaf(a[i].w, b[j].w, accK[i][j]);
          }
      }
      __syncthreads();
      #pragma unroll
      for (int it = 0; it < 4; ++it) {
        int c = it * 256 + t;
        int col = c >> 4, kq4 = c & 15;
        f32x4 vv = wv4[(size_t)(colBase + col) * 64 + kt * 16 + kq4];
        *(f32x4*)&Bs[col][kq4 * 4] = vv;
      }
      __syncthreads();
      #pragma unroll
      for (int kc = 0; kc < 16; ++kc) {
        f32x4 a[4], b[4];
        #pragma unroll
        for (int i = 0; i < 4; ++i) a[i] = *(const f32x4*)&As[ry + 16 * i][kc * 4];
        #pragma unroll
        for (int j = 0; j < 4; ++j) b[j] = *(const f32x4*)&Bs[tx + 16 * j][kc * 4];
        #pragma unroll
        for (int i = 0; i < 4; ++i)
          #pragma unroll
          for (int j = 0; j < 4; ++j) {
            accV[i][j] = fmaf(a[i].x, b[j].x, accV[i][j]);
            accV[i][j] = fmaf(a[i].y, b[j].y, accV[i][j]);
            accV[i][j] = fmaf(a[i].z, b[j].z, accV[i][j]);
            accV[i][j] = fmaf(a[i].w, b[j].w, accV[i][j]);
          }
      }
    }
    #pragma unroll
    for (int i = 0; i < 4; ++i) {
      const int r = rowBase + ry + 16 * i;
      #pragma unroll
      for (int j = 0; j < 4; ++j) {
        const int c = colBase + tx + 16 * j;
        kf[(size_t)r * 256 + c] = accK[i][j];
        kh[(size_t)r * 256 + c] = f2bf(accK[i][j]);
        vout[(size_t)r * 256 + c] = accV[i][j];
      }
    }
  }
}

// ---------------- K2: logit = qh @ kh^T (bf16 MFMA) + fused blockmax ----------------
// Round-10 proven structure verbatim.
__global__ __launch_bounds__(256) void logit_gemm(
    const unsigned short* __restrict__ qh, const unsigned short* __restrict__ kh,
    float* __restrict__ out, float* __restrict__ pmax)
{
  __shared__ short AsBuf[2][128 * 32];
  __shared__ short BsBuf[2][128 * 32];
  __shared__ float Pm[128][2];
  const int t = threadIdx.x;
  const int bid = blockIdx.x;
  const int wg = (bid & 7) * 512 + (bid >> 3);  // XCD-chunked swizzle (4096 % 8 == 0)
  const int aRow0 = (wg >> 5) * 128;            // M block
  const int bRow0 = (wg & 31) * 128;            // N block
  const int lane = t & 63, wid = t >> 6;
  const int wr = wid >> 1, wc = wid & 1;
  f32x4 acc[4][4];
  #pragma unroll
  for (int m = 0; m < 4; ++m)
    #pragma unroll
    for (int n = 0; n < 4; ++n) { acc[m][n].x = 0.f; acc[m][n].y = 0.f; acc[m][n].z = 0.f; acc[m][n].w = 0.f; }

  const short* qs = (const short*)qh;
  const short* ks = (const short*)kh;

  #define STAGE32(AB, BB, KT) do {                                          \
    _Pragma("unroll")                                                       \
    for (int ci = 0; ci < 2; ++ci) {                                        \
      int c = ci * 256 + t;                                                 \
      int row = c >> 2;                                                     \
      int slot = (c & 3) ^ (row & 3);                                       \
      int koff = (KT) * 32 + slot * 8;                                      \
      load_lds16(qs + (size_t)(aRow0 + row) * 256 + koff, (AB) + c * 8);    \
      load_lds16(ks + (size_t)(bRow0 + row) * 256 + koff, (BB) + c * 8);    \
    } } while (0)

  STAGE32(AsBuf[0], BsBuf[0], 0);
  #pragma unroll
  for (int kt = 0; kt < 8; ++kt) {
    const int buf = kt & 1;
    __syncthreads();                       // drains buf's loads; fences prev reads of buf^1
    if (kt < 7) STAGE32(AsBuf[buf ^ 1], BsBuf[buf ^ 1], kt + 1);
    const short* As = AsBuf[buf];
    const short* Bs = BsBuf[buf];
    s16x8 af[4], bfr[4];
    #pragma unroll
    for (int m = 0; m < 4; ++m) {
      int row = wr * 64 + m * 16 + (lane & 15);
      int slot = (lane >> 4) ^ (row & 3);
      af[m] = *(const s16x8*)(As + row * 32 + slot * 8);
    }
    #pragma unroll
    for (int n = 0; n < 4; ++n) {
      int row = wc * 64 + n * 16 + (lane & 15);
      int slot = (lane >> 4) ^ (row & 3);
      bfr[n] = *(const s16x8*)(Bs + row * 32 + slot * 8);
    }
    #pragma unroll
    for (int m = 0; m < 4; ++m)
      #pragma unroll
      for (int n = 0; n < 4; ++n)
        acc[m][n] = __builtin_amdgcn_mfma_f32_16x16x32_bf16(af[m], bfr[n], acc[m][n], 0, 0, 0);
  }
  #undef STAGE32

  // fused blockmax: per (row, this 128-col block) max, into Pm then pmax
  #pragma unroll
  for (int m = 0; m < 4; ++m)
    #pragma unroll
    for (int j = 0; j < 4; ++j) {
      float bm = fmaxf(fmaxf(acc[m][0][j], acc[m][1][j]),
                       fmaxf(acc[m][2][j], acc[m][3][j]));
      #pragma unroll
      for (int off = 1; off < 16; off <<= 1) bm = fmaxf(bm, __shfl_xor(bm, off));
      if ((lane & 15) == 0) Pm[wr * 64 + m * 16 + (lane >> 4) * 4 + j][wc] = bm;
    }
  // logit store (proven scalar epilogue — L2 merges the 64B segments)
  const int colLane = lane & 15, rowQuad = (lane >> 4) * 4;
  #pragma unroll
  for (int m = 0; m < 4; ++m)
    #pragma unroll
    for (int n = 0; n < 4; ++n) {
      int row = aRow0 + wr * 64 + m * 16 + rowQuad;
      int col = bRow0 + wc * 64 + n * 16 + colLane;
      #pragma unroll
      for (int j = 0; j < 4; ++j)
        out[(size_t)(row + j) * 4096 + col] = acc[m][n][j];
    }
  __syncthreads();
  if (t < 128) pmax[(size_t)(aRow0 + t) * 32 + (bRow0 >> 7)] = fmaxf(Pm[t][0], Pm[t][1]);
}

// ---------------- K3: finalize — single-candidate fast path + exact recheck fallback ----------------
__global__ __launch_bounds__(1024) void finalize_kernel(
    const float* __restrict__ logit, const float* __restrict__ pmax,
    const float* __restrict__ qf, const float* __restrict__ kf,
    const float* __restrict__ vout, float* __restrict__ quant, float* __restrict__ code)
{
  __shared__ __align__(16) float Vs[32][260];
  __shared__ int idxArr[32];
  const int t = threadIdx.x, wave = t >> 6, lane = t & 63;
  const int nh = blockIdx.x, n = nh >> 5, h = nh & 31;
  for (int ri = 0; ri < 2; ++ri) {
    const int w = wave * 2 + ri;
    const size_t r = (size_t)nh * 32 + w;
    float pv = -3e38f;
    if (lane < 32) pv = pmax[r * 32 + lane];
    float gmax = pv;
    #pragma unroll
    for (int off = 32; off; off >>= 1) gmax = fmaxf(gmax, __shfl_xor(gmax, off));
    const float thr = gmax - ARGMAX_MARGIN;
    const unsigned long long bmAll = __ballot(pv >= thr);  // candidate 128-col blocks
    int tot = 0, firstJ = 0x7fffffff;
    {
      unsigned long long bm = bmAll;
      #pragma unroll 1
      while (bm) {
        const int nb = __ffsll(bm) - 1; bm &= bm - 1;
        const float2 lv = *(const float2*)&logit[r * 4096 + nb * 128 + lane * 2];
        unsigned long long c0 = __ballot(lv.x >= thr);
        unsigned long long c1 = __ballot(lv.y >= thr);
        tot += __popcll(c0) + __popcll(c1);
        if (firstJ == 0x7fffffff && (c0 | c1)) {
          int j0 = c0 ? nb * 128 + 2 * (__ffsll(c0) - 1)     : 0x7fffffff;
          int j1 = c1 ? nb * 128 + 2 * (__ffsll(c1) - 1) + 1 : 0x7fffffff;
          firstJ = j0 < j1 ? j0 : j1;
        }
      }
    }
    int bestJ = firstJ;
    if (tot > 1) {     // slow path: exact f64 recheck of every candidate
      const f32x4 qv = ((const f32x4*)(qf + r * 256))[lane];
      float bestV = -3e38f; bestJ = 0x7fffffff;
      unsigned long long bm = bmAll;
      #pragma unroll 1
      while (bm) {
        const int nb = __ffsll(bm) - 1; bm &= bm - 1;
        const float2 lv = *(const float2*)&logit[r * 4096 + nb * 128 + lane * 2];
        unsigned long long c0 = __ballot(lv.x >= thr);
        unsigned long long c1 = __ballot(lv.y >= thr);
        #pragma unroll 1
        for (int half = 0; half < 2; ++half) {
          unsigned long long mm = half ? c1 : c0;
          #pragma unroll 1
          while (mm) {
            const int L = __ffsll(mm) - 1; mm &= mm - 1;
            const int j = nb * 128 + L * 2 + half;
            const f32x4 kv = ((const f32x4*)(kf + (size_t)j * 256))[lane];
            double s = (double)qv.x * kv.x + (double)qv.y * kv.y
                     + (double)qv.z * kv.z + (double)qv.w * kv.w;
            #pragma unroll
            for (int off = 32; off; off >>= 1) s += __shfl_xor(s, off);
            const float val = (float)(s * 0.0625);
            if (val > bestV || (val == bestV && j < bestJ)) { bestV = val; bestJ = j; }
          }
        }
      }
    }
    if (lane == 0) idxArr[w] = bestJ;
  }
  __syncthreads();
  for (int ri = 0; ri < 2; ++ri) {
    const int w2 = wave * 2 + ri;
    const int idx = idxArr[w2];
    const f32x4 vv = ((const f32x4*)(vout + (size_t)idx * 256))[lane];
    *(f32x4*)&Vs[w2][lane * 4] = vv;
  }
  __syncthreads();
  const int wcol = t & 31, cg = t >> 5;
  #pragma unroll
  for (int cc = 0; cc < 8; ++cc) {
    const int c = cg * 8 + cc;
    quant[(((size_t)n * 256 + c) * 32 + h) * 32 + wcol] = Vs[wcol][c];
  }
  if (t < 32) code[nh * 32 + t] = (float)(idxArr[t] & 255);
}

extern "C" void kernel_launch(void* const* d_in, const int* in_sizes, int n_in,
                              void* d_out, int out_size, void* d_ws, size_t ws_size,
                              hipStream_t stream) {
  (void)in_sizes; (void)n_in; (void)out_size; (void)ws_size;
  const float* latent = (const float*)d_in[0];
  const float* cb     = (const float*)d_in[1];
  const float* wq     = (const float*)d_in[2];
  const float* wk     = (const float*)d_in[3];
  const float* wv     = (const float*)d_in[4];

  float* out   = (float*)d_out;
  float* quant = out + QUANT_OFF;
  float* code  = out + CODE_OFF;
  float* logit = out + LOGIT_OFF;
  float* vout  = out + V_OFF;

  char* ws = (char*)d_ws;
  float*          qf   = (float*)(ws + 0);                 // 16 MB
  float*          kf   = (float*)(ws + 16777216);          // 4 MB
  unsigned short* qh   = (unsigned short*)(ws + 20971520); // 8 MB
  unsigned short* kh   = (unsigned short*)(ws + 29360128); // 2 MB
  float*          pmax = (float*)(ws + 31457280);          // 2 MB (16384 x 32), ends at 32 MB

  kvq_kernel<<<1280, 256, 0, stream>>>(latent, wq, cb, wk, wv, qf, qh, kf, kh, vout);
  logit_gemm<<<4096, 256, 0, stream>>>(qh, kh, logit, pmax);
  finalize_kernel<<<512, 1024, 0, stream>>>(logit, pmax, qf, kf, vout, quant, code);
}

// Round 16
// 170.212 us; speedup vs baseline: 1.8878x; 1.0013x over previous
//
#include <hip/hip_runtime.h>
#include <stdint.h>

typedef float f32x4 __attribute__((ext_vector_type(4)));
typedef short s16x8 __attribute__((ext_vector_type(8)));

// N=16, C=256, H=32, W=32, K=4096, M = N*H*W = 16384
// d_out layout (floats): quant[4194304] | code[16384] | logit[67108864] | v[1048576]
#define QUANT_OFF 0
#define CODE_OFF  4194304
#define LOGIT_OFF 4210688
#define V_OFF     71319552

// logit std ~= 0.0625 (codebook prescaled by 1/sqrt(C)); bf16-path absmax err 0.00195.
// Margin must exceed 2*err (0.0039); use 1/128 for 2x headroom.
#define ARGMAX_MARGIN 0.0078125f

__device__ __forceinline__ unsigned short f2bf(float f) {
  unsigned int u = __float_as_uint(f);
  u = u + 0x7fffu + ((u >> 16) & 1u);   // RNE
  return (unsigned short)(u >> 16);
}

__device__ __forceinline__ void load_lds16(const void* g, void* l) {
  __builtin_amdgcn_global_load_lds(
      (const __attribute__((address_space(1))) unsigned int*)g,
      (__attribute__((address_space(3))) unsigned int*)l, 16, 0, 0);
}

// ---------------- K1: fp32 VALU GEMMs, uniform BK=32 dbuf skeleton ----------------
// blocks 0..255: k = cb@wk^T | 256..511: v = cb@wv^T | 512..1535: q = x@wq^T.
// One __syncthreads per K-step; next tile's global_load_lds fly under the FMAs.
// All LDS unpadded (32 KB total): A/B staged via global_load_lds w=16 with XOR
// slot swizzle (linear dest + swizzled source + swizzled read) -> conflict-free.
__global__ __launch_bounds__(256) void kvq_kernel(
    const float* __restrict__ latent, const float* __restrict__ wq,
    const float* __restrict__ cb, const float* __restrict__ wk, const float* __restrict__ wv,
    float* __restrict__ qf, unsigned short* __restrict__ qh,
    float* __restrict__ kf, unsigned short* __restrict__ kh, float* __restrict__ vout)
{
  __shared__ __align__(16) float A_s[2][2048];   // q: [k 32][row 64]; kv: [row 64][k 32] swz
  __shared__ __align__(16) float B_s[2][2048];   // [col 64][k 32] swz
  const int t = threadIdx.x;
  const int bid = blockIdx.x;
  const int tx = t & 15;
  const int ry = t >> 4;  // 0..15

  if (bid >= 512) {
    // ---------------- q path ----------------
    const int qb = bid - 512;
    const int rowBase = (qb & 255) * 64;
    const int colBase = (qb >> 8) * 64;
    const int n = rowBase >> 10;
    const int hw0 = rowBase & 1023;
    float acc[4][4] = {{0.f}};

    // A: chunk c -> k=c>>4, rows (c&15)*4.. (k-major, linear, no transpose needed)
    // B: chunk c -> col=c>>3, lslot=c&7; source k-chunk = lslot ^ (col&7)
    #define QSTAGE(B, KT) do {                                                        \
      _Pragma("unroll")                                                               \
      for (int it = 0; it < 2; ++it) {                                                \
        int c = it * 256 + t;                                                         \
        int kk = c >> 4, rq = c & 15;                                                 \
        load_lds16(latent + ((size_t)(n * 256 + (KT) * 32 + kk) * 1024 + hw0 + rq * 4), \
                   &A_s[B][c * 4]);                                                   \
        int col = c >> 3, ls = c & 7;                                                 \
        int sk = ls ^ (col & 7);                                                      \
        load_lds16(wq + ((size_t)(colBase + col) * 256 + (KT) * 32 + sk * 4),          \
                   &B_s[B][c * 4]);                                                   \
      } } while (0)

    QSTAGE(0, 0);
    #pragma unroll 1
    for (int kt = 0; kt < 8; ++kt) {
      const int buf = kt & 1;
      __syncthreads();                      // drains buf's loads; fences prev reads
      if (kt < 7) QSTAGE(buf ^ 1, kt + 1);  // prefetch flies under FMAs
      const float* As = A_s[buf];
      const float* Bs = B_s[buf];
      #pragma unroll
      for (int kc = 0; kc < 8; ++kc) {
        f32x4 a[4], b[4];
        #pragma unroll
        for (int c = 0; c < 4; ++c) a[c] = *(const f32x4*)&As[(kc * 4 + c) * 64 + ry * 4];
        #pragma unroll
        for (int j = 0; j < 4; ++j) {
          const int col = tx + 16 * j;
          b[j] = *(const f32x4*)&Bs[col * 32 + (kc ^ (col & 7)) * 4];
        }
        #pragma unroll
        for (int i = 0; i < 4; ++i)
          #pragma unroll
          for (int j = 0; j < 4; ++j) {
            acc[i][j] = fmaf(a[0][i], b[j].x, acc[i][j]);
            acc[i][j] = fmaf(a[1][i], b[j].y, acc[i][j]);
            acc[i][j] = fmaf(a[2][i], b[j].z, acc[i][j]);
            acc[i][j] = fmaf(a[3][i], b[j].w, acc[i][j]);
          }
      }
    }
    #undef QSTAGE
    #pragma unroll
    for (int i = 0; i < 4; ++i) {
      const int r = rowBase + ry * 4 + i;
      #pragma unroll
      for (int j = 0; j < 4; ++j) {
        const int c = colBase + tx + 16 * j;
        qf[(size_t)r * 256 + c] = acc[i][j];
        qh[(size_t)r * 256 + c] = f2bf(acc[i][j] * 0.0625f);
      }
    }
  } else {
    // ---------------- k / v paths ----------------
    const bool isV = bid >= 256;
    const int kb = bid & 255;
    const int rowBase = (kb & 63) * 64;
    const int colBase = (kb >> 6) * 64;
    const float* W = isV ? wv : wk;
    float acc[4][4] = {{0.f}};

    // A: chunk c -> row=c>>3, lslot=c&7; source k-chunk = lslot ^ (row&7). B same.
    #define KSTAGE(B, KT) do {                                                        \
      _Pragma("unroll")                                                               \
      for (int it = 0; it < 2; ++it) {                                                \
        int c = it * 256 + t;                                                         \
        int row = c >> 3, ls = c & 7;                                                 \
        int sk = ls ^ (row & 7);                                                      \
        load_lds16(cb + ((size_t)(rowBase + row) * 256 + (KT) * 32 + sk * 4),          \
                   &A_s[B][c * 4]);                                                   \
        load_lds16(W  + ((size_t)(colBase + row) * 256 + (KT) * 32 + sk * 4),          \
                   &B_s[B][c * 4]);                                                   \
      } } while (0)

    KSTAGE(0, 0);
    #pragma unroll 1
    for (int kt = 0; kt < 8; ++kt) {
      const int buf = kt & 1;
      __syncthreads();
      if (kt < 7) KSTAGE(buf ^ 1, kt + 1);
      const float* As = A_s[buf];
      const float* Bs = B_s[buf];
      #pragma unroll
      for (int kc = 0; kc < 8; ++kc) {
        f32x4 a[4], b[4];
        #pragma unroll
        for (int i = 0; i < 4; ++i) {
          const int row = ry + 16 * i;
          a[i] = *(const f32x4*)&As[row * 32 + (kc ^ (row & 7)) * 4];
        }
        #pragma unroll
        for (int j = 0; j < 4; ++j) {
          const int col = tx + 16 * j;
          b[j] = *(const f32x4*)&Bs[col * 32 + (kc ^ (col & 7)) * 4];
        }
        #pragma unroll
        for (int i = 0; i < 4; ++i)
          #pragma unroll
          for (int j = 0; j < 4; ++j) {
            acc[i][j] = fmaf(a[i].x, b[j].x, acc[i][j]);
            acc[i][j] = fmaf(a[i].y, b[j].y, acc[i][j]);
            acc[i][j] = fmaf(a[i].z, b[j].z, acc[i][j]);
            acc[i][j] = fmaf(a[i].w, b[j].w, acc[i][j]);
          }
      }
    }
    #undef KSTAGE
    #pragma unroll
    for (int i = 0; i < 4; ++i) {
      const int r = rowBase + ry + 16 * i;
      #pragma unroll
      for (int j = 0; j < 4; ++j) {
        const int c = colBase + tx + 16 * j;
        if (isV) {
          vout[(size_t)r * 256 + c] = acc[i][j];
        } else {
          kf[(size_t)r * 256 + c] = acc[i][j];
          kh[(size_t)r * 256 + c] = f2bf(acc[i][j]);
        }
      }
    }
  }
}

// ---------------- K2: logit = qh @ kh^T (bf16 MFMA) + fused blockmax ----------------
// Round-10 proven structure verbatim.
__global__ __launch_bounds__(256) void logit_gemm(
    const unsigned short* __restrict__ qh, const unsigned short* __restrict__ kh,
    float* __restrict__ out, float* __restrict__ pmax)
{
  __shared__ short AsBuf[2][128 * 32];
  __shared__ short BsBuf[2][128 * 32];
  __shared__ float Pm[128][2];
  const int t = threadIdx.x;
  const int bid = blockIdx.x;
  const int wg = (bid & 7) * 512 + (bid >> 3);  // XCD-chunked swizzle (4096 % 8 == 0)
  const int aRow0 = (wg >> 5) * 128;            // M block
  const int bRow0 = (wg & 31) * 128;            // N block
  const int lane = t & 63, wid = t >> 6;
  const int wr = wid >> 1, wc = wid & 1;
  f32x4 acc[4][4];
  #pragma unroll
  for (int m = 0; m < 4; ++m)
    #pragma unroll
    for (int n = 0; n < 4; ++n) { acc[m][n].x = 0.f; acc[m][n].y = 0.f; acc[m][n].z = 0.f; acc[m][n].w = 0.f; }

  const short* qs = (const short*)qh;
  const short* ks = (const short*)kh;

  #define STAGE32(AB, BB, KT) do {                                          \
    _Pragma("unroll")                                                       \
    for (int ci = 0; ci < 2; ++ci) {                                        \
      int c = ci * 256 + t;                                                 \
      int row = c >> 2;                                                     \
      int slot = (c & 3) ^ (row & 3);                                       \
      int koff = (KT) * 32 + slot * 8;                                      \
      load_lds16(qs + (size_t)(aRow0 + row) * 256 + koff, (AB) + c * 8);    \
      load_lds16(ks + (size_t)(bRow0 + row) * 256 + koff, (BB) + c * 8);    \
    } } while (0)

  STAGE32(AsBuf[0], BsBuf[0], 0);
  #pragma unroll
  for (int kt = 0; kt < 8; ++kt) {
    const int buf = kt & 1;
    __syncthreads();                       // drains buf's loads; fences prev reads of buf^1
    if (kt < 7) STAGE32(AsBuf[buf ^ 1], BsBuf[buf ^ 1], kt + 1);
    const short* As = AsBuf[buf];
    const short* Bs = BsBuf[buf];
    s16x8 af[4], bfr[4];
    #pragma unroll
    for (int m = 0; m < 4; ++m) {
      int row = wr * 64 + m * 16 + (lane & 15);
      int slot = (lane >> 4) ^ (row & 3);
      af[m] = *(const s16x8*)(As + row * 32 + slot * 8);
    }
    #pragma unroll
    for (int n = 0; n < 4; ++n) {
      int row = wc * 64 + n * 16 + (lane & 15);
      int slot = (lane >> 4) ^ (row & 3);
      bfr[n] = *(const s16x8*)(Bs + row * 32 + slot * 8);
    }
    #pragma unroll
    for (int m = 0; m < 4; ++m)
      #pragma unroll
      for (int n = 0; n < 4; ++n)
        acc[m][n] = __builtin_amdgcn_mfma_f32_16x16x32_bf16(af[m], bfr[n], acc[m][n], 0, 0, 0);
  }
  #undef STAGE32

  // fused blockmax: per (row, this 128-col block) max, into Pm then pmax
  #pragma unroll
  for (int m = 0; m < 4; ++m)
    #pragma unroll
    for (int j = 0; j < 4; ++j) {
      float bm = fmaxf(fmaxf(acc[m][0][j], acc[m][1][j]),
                       fmaxf(acc[m][2][j], acc[m][3][j]));
      #pragma unroll
      for (int off = 1; off < 16; off <<= 1) bm = fmaxf(bm, __shfl_xor(bm, off));
      if ((lane & 15) == 0) Pm[wr * 64 + m * 16 + (lane >> 4) * 4 + j][wc] = bm;
    }
  // logit store (proven scalar epilogue — L2 merges the 64B segments)
  const int colLane = lane & 15, rowQuad = (lane >> 4) * 4;
  #pragma unroll
  for (int m = 0; m < 4; ++m)
    #pragma unroll
    for (int n = 0; n < 4; ++n) {
      int row = aRow0 + wr * 64 + m * 16 + rowQuad;
      int col = bRow0 + wc * 64 + n * 16 + colLane;
      #pragma unroll
      for (int j = 0; j < 4; ++j)
        out[(size_t)(row + j) * 4096 + col] = acc[m][n][j];
    }
  __syncthreads();
  if (t < 128) pmax[(size_t)(aRow0 + t) * 32 + (bRow0 >> 7)] = fmaxf(Pm[t][0], Pm[t][1]);
}

// ---------------- K3: finalize — single-candidate fast path + exact recheck fallback ----------------
__global__ __launch_bounds__(1024) void finalize_kernel(
    const float* __restrict__ logit, const float* __restrict__ pmax,
    const float* __restrict__ qf, const float* __restrict__ kf,
    const float* __restrict__ vout, float* __restrict__ quant, float* __restrict__ code)
{
  __shared__ __align__(16) float Vs[32][260];
  __shared__ int idxArr[32];
  const int t = threadIdx.x, wave = t >> 6, lane = t & 63;
  const int nh = blockIdx.x, n = nh >> 5, h = nh & 31;
  for (int ri = 0; ri < 2; ++ri) {
    const int w = wave * 2 + ri;
    const size_t r = (size_t)nh * 32 + w;
    float pv = -3e38f;
    if (lane < 32) pv = pmax[r * 32 + lane];
    float gmax = pv;
    #pragma unroll
    for (int off = 32; off; off >>= 1) gmax = fmaxf(gmax, __shfl_xor(gmax, off));
    const float thr = gmax - ARGMAX_MARGIN;
    const unsigned long long bmAll = __ballot(pv >= thr);  // candidate 128-col blocks
    int tot = 0, firstJ = 0x7fffffff;
    {
      unsigned long long bm = bmAll;
      #pragma unroll 1
      while (bm) {
        const int nb = __ffsll(bm) - 1; bm &= bm - 1;
        const float2 lv = *(const float2*)&logit[r * 4096 + nb * 128 + lane * 2];
        unsigned long long c0 = __ballot(lv.x >= thr);
        unsigned long long c1 = __ballot(lv.y >= thr);
        tot += __popcll(c0) + __popcll(c1);
        if (firstJ == 0x7fffffff && (c0 | c1)) {
          int j0 = c0 ? nb * 128 + 2 * (__ffsll(c0) - 1)     : 0x7fffffff;
          int j1 = c1 ? nb * 128 + 2 * (__ffsll(c1) - 1) + 1 : 0x7fffffff;
          firstJ = j0 < j1 ? j0 : j1;
        }
      }
    }
    int bestJ = firstJ;
    if (tot > 1) {     // slow path: exact f64 recheck of every candidate
      const f32x4 qv = ((const f32x4*)(qf + r * 256))[lane];
      float bestV = -3e38f; bestJ = 0x7fffffff;
      unsigned long long bm = bmAll;
      #pragma unroll 1
      while (bm) {
        const int nb = __ffsll(bm) - 1; bm &= bm - 1;
        const float2 lv = *(const float2*)&logit[r * 4096 + nb * 128 + lane * 2];
        unsigned long long c0 = __ballot(lv.x >= thr);
        unsigned long long c1 = __ballot(lv.y >= thr);
        #pragma unroll 1
        for (int half = 0; half < 2; ++half) {
          unsigned long long mm = half ? c1 : c0;
          #pragma unroll 1
          while (mm) {
            const int L = __ffsll(mm) - 1; mm &= mm - 1;
            const int j = nb * 128 + L * 2 + half;
            const f32x4 kv = ((const f32x4*)(kf + (size_t)j * 256))[lane];
            double s = (double)qv.x * kv.x + (double)qv.y * kv.y
                     + (double)qv.z * kv.z + (double)qv.w * kv.w;
            #pragma unroll
            for (int off = 32; off; off >>= 1) s += __shfl_xor(s, off);
            const float val = (float)(s * 0.0625);
            if (val > bestV || (val == bestV && j < bestJ)) { bestV = val; bestJ = j; }
          }
        }
      }
    }
    if (lane == 0) idxArr[w] = bestJ;
  }
  __syncthreads();
  for (int ri = 0; ri < 2; ++ri) {
    const int w2 = wave * 2 + ri;
    const int idx = idxArr[w2];
    const f32x4 vv = ((const f32x4*)(vout + (size_t)idx * 256))[lane];
    *(f32x4*)&Vs[w2][lane * 4] = vv;
  }
  __syncthreads();
  const int wcol = t & 31, cg = t >> 5;
  #pragma unroll
  for (int cc = 0; cc < 8; ++cc) {
    const int c = cg * 8 + cc;
    quant[(((size_t)n * 256 + c) * 32 + h) * 32 + wcol] = Vs[wcol][c];
  }
  if (t < 32) code[nh * 32 + t] = (float)(idxArr[t] & 255);
}

extern "C" void kernel_launch(void* const* d_in, const int* in_sizes, int n_in,
                              void* d_out, int out_size, void* d_ws, size_t ws_size,
                              hipStream_t stream) {
  (void)in_sizes; (void)n_in; (void)out_size; (void)ws_size;
  const float* latent = (const float*)d_in[0];
  const float* cb     = (const float*)d_in[1];
  const float* wq     = (const float*)d_in[2];
  const float* wk     = (const float*)d_in[3];
  const float* wv     = (const float*)d_in[4];

  float* out   = (float*)d_out;
  float* quant = out + QUANT_OFF;
  float* code  = out + CODE_OFF;
  float* logit = out + LOGIT_OFF;
  float* vout  = out + V_OFF;

  char* ws = (char*)d_ws;
  float*          qf   = (float*)(ws + 0);                 // 16 MB
  float*          kf   = (float*)(ws + 16777216);          // 4 MB
  unsigned short* qh   = (unsigned short*)(ws + 20971520); // 8 MB
  unsigned short* kh   = (unsigned short*)(ws + 29360128); // 2 MB
  float*          pmax = (float*)(ws + 31457280);          // 2 MB (16384 x 32), ends at 32 MB

  kvq_kernel<<<1536, 256, 0, stream>>>(latent, wq, cb, wk, wv, qf, qh, kf, kh, vout);
  logit_gemm<<<4096, 256, 0, stream>>>(qh, kh, logit, pmax);
  finalize_kernel<<<512, 1024, 0, stream>>>(logit, pmax, qf, kf, vout, quant, code);
}